// Round 1
// baseline (876.937 us; speedup 1.0000x reference)
//
#include <hip/hip_runtime.h>
#include <hip/hip_bf16.h>

#define NTOK 8192
#define HID 2048
#define INTER 768
#define NEXP 16

typedef __bf16 bf16x8 __attribute__((ext_vector_type(8)));
typedef float f32x4 __attribute__((ext_vector_type(4)));

typedef const __attribute__((address_space(1))) void gvoid_t;
typedef __attribute__((address_space(3))) void lvoid_t;

static __device__ __forceinline__ void load_lds16(const void* g, void* l) {
  __builtin_amdgcn_global_load_lds((gvoid_t*)g, (lvoid_t*)l, 16, 0, 0);
}

static __device__ __forceinline__ unsigned short f2bf(float f) {
  unsigned int u = __float_as_uint(f);
  u += 0x7FFFu + ((u >> 16) & 1u);
  return (unsigned short)(u >> 16);
}

// ---------------- fp32 -> bf16 conversion ----------------
__global__ __launch_bounds__(256) void cvt_kernel(const float* __restrict__ src,
                                                  unsigned short* __restrict__ dst, int n) {
  int i = (blockIdx.x * 256 + threadIdx.x) * 4;
  int stride = gridDim.x * 256 * 4;
  for (; i < n; i += stride) {
    float4 v = *reinterpret_cast<const float4*>(src + i);
    ushort4 o;
    o.x = f2bf(v.x); o.y = f2bf(v.y); o.z = f2bf(v.z); o.w = f2bf(v.w);
    *reinterpret_cast<ushort4*>(dst + i) = o;
  }
}

// ---------------- router: logits + top2 + combine weights ----------------
__global__ __launch_bounds__(256) void router_kernel(const float* __restrict__ x,
                                                     const float* __restrict__ gw,
                                                     int* __restrict__ counts,
                                                     int* __restrict__ te,
                                                     float* __restrict__ tw) {
  const int lane = threadIdx.x & 63;
  const int wid = threadIdx.x >> 6;
  const int t = blockIdx.x * 4 + wid;
  float acc[NEXP];
#pragma unroll
  for (int e = 0; e < NEXP; ++e) acc[e] = 0.f;
  const float* xp = x + (size_t)t * HID;
#pragma unroll 4
  for (int j = 0; j < HID / 64; ++j) {
    float xv = xp[lane + 64 * j];
#pragma unroll
    for (int e = 0; e < NEXP; ++e) acc[e] += xv * gw[e * HID + lane + 64 * j];
  }
#pragma unroll
  for (int e = 0; e < NEXP; ++e) {
#pragma unroll
    for (int m = 32; m >= 1; m >>= 1) acc[e] += __shfl_xor(acc[e], m);
  }
  if (lane == 0) {
    float b0 = -1e30f; int i0 = 0;
#pragma unroll
    for (int e = 0; e < NEXP; ++e) { if (acc[e] > b0) { b0 = acc[e]; i0 = e; } }
    float b1 = -1e30f; int i1 = 0;
#pragma unroll
    for (int e = 0; e < NEXP; ++e) { if (e != i0 && acc[e] > b1) { b1 = acc[e]; i1 = e; } }
    float w0 = 1.f / (1.f + __expf(b1 - b0));  // = p0/(p0+p1), softmax Z cancels
    te[2 * t] = i0; te[2 * t + 1] = i1;
    tw[2 * t] = w0; tw[2 * t + 1] = 1.f - w0;
    atomicAdd(&counts[i0], 1);
    atomicAdd(&counts[i1], 1);
  }
}

// ---------------- prefix scan over 16 expert counts ----------------
__global__ void scan_kernel(const int* __restrict__ counts, int* __restrict__ offsets,
                            int* __restrict__ cursors) {
  if (threadIdx.x == 0) {
    int run = 0;
    for (int e = 0; e < NEXP; ++e) { offsets[e] = run; cursors[e] = run; run += counts[e]; }
  }
}

// ---------------- scatter tokens into per-expert flat lists ----------------
__global__ __launch_bounds__(256) void scatter_kernel(const int* __restrict__ te,
                                                      const float* __restrict__ tw,
                                                      int* __restrict__ cursors,
                                                      int* __restrict__ tok_flat,
                                                      float* __restrict__ w_flat) {
  int t = blockIdx.x * 256 + threadIdx.x;
  if (t >= NTOK) return;
#pragma unroll
  for (int k = 0; k < 2; ++k) {
    int e = te[2 * t + k];
    int pos = atomicAdd(&cursors[e], 1);
    tok_flat[pos] = t;
    w_flat[pos] = tw[2 * t + k];
  }
}

// ---------------- gemm1: H = silu(X Wg^T) * (X Wu^T), gathered rows ----------------
__global__ __launch_bounds__(256) void gemm1_kernel(
    const unsigned short* __restrict__ Xb,   // [NTOK][HID] bf16
    const unsigned short* __restrict__ Wg,   // [NEXP][INTER][HID] bf16
    const unsigned short* __restrict__ Wu,
    const int* __restrict__ counts, const int* __restrict__ offsets,
    const int* __restrict__ tok_flat,
    unsigned short* __restrict__ Hf) {       // [2*NTOK][INTER] bf16
  const int e = blockIdx.z;
  const int cnt = counts[e];
  const int m0 = blockIdx.y * 128;
  if (m0 >= cnt) return;
  const int off = offsets[e];
  const int n0 = blockIdx.x * 128;

  __shared__ __align__(16) unsigned short As[128 * 64];
  __shared__ __align__(16) unsigned short Bgs[128 * 64];
  __shared__ __align__(16) unsigned short Bus[128 * 64];

  const int tid = threadIdx.x;
  const int lane = tid & 63;
  const int wid = tid >> 6;
  const int brow = tid >> 3;       // 0..31
  const int c8 = (tid & 7) * 8;    // bf16 col offset within BK=64

  const unsigned short* xrow[4];
#pragma unroll
  for (int it = 0; it < 4; ++it) {
    int r = it * 32 + brow;
    int s = (m0 + r < cnt) ? (off + m0 + r) : off;  // clamp pad rows (stores guarded)
    xrow[it] = Xb + (size_t)tok_flat[s] * HID + c8;
  }
  const unsigned short* grow = Wg + ((size_t)e * INTER + n0) * HID + c8;
  const unsigned short* urow = Wu + ((size_t)e * INTER + n0) * HID + c8;

  f32x4 zero = {0.f, 0.f, 0.f, 0.f};
  f32x4 accG[4][4], accU[4][4];
#pragma unroll
  for (int i = 0; i < 4; ++i) {
#pragma unroll
    for (int j = 0; j < 4; ++j) { accG[i][j] = zero; accU[i][j] = zero; }
  }

  const int wm = (wid >> 1) * 64;
  const int wn = (wid & 1) * 64;
  const int fr = lane & 15;
  const int fc = (lane >> 4) * 8;

  for (int kt = 0; kt < HID; kt += 64) {
#pragma unroll
    for (int it = 0; it < 4; ++it) {
      int row = it * 32 + brow;
      load_lds16(xrow[it] + kt, As + row * 64 + c8);
      load_lds16(grow + (size_t)row * HID + kt, Bgs + row * 64 + c8);
      load_lds16(urow + (size_t)row * HID + kt, Bus + row * 64 + c8);
    }
    __syncthreads();
#pragma unroll
    for (int kk = 0; kk < 2; ++kk) {
      bf16x8 af[4], bgf[4], buf_[4];
#pragma unroll
      for (int i = 0; i < 4; ++i) {
        af[i]   = *reinterpret_cast<const bf16x8*>(As  + (wm + i * 16 + fr) * 64 + kk * 32 + fc);
        bgf[i]  = *reinterpret_cast<const bf16x8*>(Bgs + (wn + i * 16 + fr) * 64 + kk * 32 + fc);
        buf_[i] = *reinterpret_cast<const bf16x8*>(Bus + (wn + i * 16 + fr) * 64 + kk * 32 + fc);
      }
#pragma unroll
      for (int i = 0; i < 4; ++i) {
#pragma unroll
        for (int j = 0; j < 4; ++j) {
          accG[i][j] = __builtin_amdgcn_mfma_f32_16x16x32_bf16(af[i], bgf[j], accG[i][j], 0, 0, 0);
          accU[i][j] = __builtin_amdgcn_mfma_f32_16x16x32_bf16(af[i], buf_[j], accU[i][j], 0, 0, 0);
        }
      }
    }
    __syncthreads();
  }

  // epilogue: silu(g)*u -> bf16 H. D frag: row=(lane>>4)*4+reg, col=lane&15
  const int lr = (lane >> 4) * 4;
  const int lc = lane & 15;
#pragma unroll
  for (int i = 0; i < 4; ++i) {
#pragma unroll
    for (int r = 0; r < 4; ++r) {
      int m = wm + i * 16 + lr + r;
      if (m0 + m < cnt) {
        size_t base = (size_t)(off + m0 + m) * INTER + (size_t)(n0 + wn + lc);
#pragma unroll
        for (int j = 0; j < 4; ++j) {
          float g = accG[i][j][r];
          float u = accU[i][j][r];
          float h = g / (1.f + __expf(-g)) * u;
          Hf[base + j * 16] = f2bf(h);
        }
      }
    }
  }
}

// ---------------- gemm2: out[t] += w * (H Wd^T) ----------------
__global__ __launch_bounds__(256) void gemm2_kernel(
    const unsigned short* __restrict__ Hf,   // [2*NTOK][INTER] bf16
    const unsigned short* __restrict__ Wd,   // [NEXP][HID][INTER] bf16
    const int* __restrict__ counts, const int* __restrict__ offsets,
    const int* __restrict__ tok_flat, const float* __restrict__ w_flat,
    float* __restrict__ out) {
  const int e = blockIdx.z;
  const int cnt = counts[e];
  const int m0 = blockIdx.y * 128;
  if (m0 >= cnt) return;
  const int off = offsets[e];
  const int n0 = blockIdx.x * 128;

  __shared__ __align__(16) unsigned short As[128 * 64];
  __shared__ __align__(16) unsigned short Bs[128 * 64];

  const int tid = threadIdx.x;
  const int lane = tid & 63;
  const int wid = tid >> 6;
  const int brow = tid >> 3;
  const int c8 = (tid & 7) * 8;

  const unsigned short* hrow[4];
#pragma unroll
  for (int it = 0; it < 4; ++it) {
    int r = it * 32 + brow;
    int s = (m0 + r < cnt) ? (off + m0 + r) : off;
    hrow[it] = Hf + (size_t)s * INTER + c8;
  }
  const unsigned short* wrow = Wd + ((size_t)e * HID + n0) * INTER + c8;

  f32x4 zero = {0.f, 0.f, 0.f, 0.f};
  f32x4 acc[4][4];
#pragma unroll
  for (int i = 0; i < 4; ++i) {
#pragma unroll
    for (int j = 0; j < 4; ++j) acc[i][j] = zero;
  }

  const int wm = (wid >> 1) * 64;
  const int wn = (wid & 1) * 64;
  const int fr = lane & 15;
  const int fc = (lane >> 4) * 8;

  for (int kt = 0; kt < INTER; kt += 64) {
#pragma unroll
    for (int it = 0; it < 4; ++it) {
      int row = it * 32 + brow;
      load_lds16(hrow[it] + kt, As + row * 64 + c8);
      load_lds16(wrow + (size_t)row * INTER + kt, Bs + row * 64 + c8);
    }
    __syncthreads();
#pragma unroll
    for (int kk = 0; kk < 2; ++kk) {
      bf16x8 af[4], bf_[4];
#pragma unroll
      for (int i = 0; i < 4; ++i) {
        af[i]  = *reinterpret_cast<const bf16x8*>(As + (wm + i * 16 + fr) * 64 + kk * 32 + fc);
        bf_[i] = *reinterpret_cast<const bf16x8*>(Bs + (wn + i * 16 + fr) * 64 + kk * 32 + fc);
      }
#pragma unroll
      for (int i = 0; i < 4; ++i) {
#pragma unroll
        for (int j = 0; j < 4; ++j) {
          acc[i][j] = __builtin_amdgcn_mfma_f32_16x16x32_bf16(af[i], bf_[j], acc[i][j], 0, 0, 0);
        }
      }
    }
    __syncthreads();
  }

  const int lr = (lane >> 4) * 4;
  const int lc = lane & 15;
#pragma unroll
  for (int i = 0; i < 4; ++i) {
#pragma unroll
    for (int r = 0; r < 4; ++r) {
      int m = wm + i * 16 + lr + r;
      if (m0 + m < cnt) {
        int slot = off + m0 + m;
        int t = tok_flat[slot];
        float w = w_flat[slot];
        float* op = out + (size_t)t * HID + (size_t)(n0 + wn + lc);
#pragma unroll
        for (int j = 0; j < 4; ++j) {
          atomicAdd(op + j * 16, w * acc[i][j][r]);
        }
      }
    }
  }
}

// ---------------- launch ----------------
extern "C" void kernel_launch(void* const* d_in, const int* in_sizes, int n_in,
                              void* d_out, int out_size, void* d_ws, size_t ws_size,
                              hipStream_t stream) {
  const float* x  = (const float*)d_in[0];
  const float* gw = (const float*)d_in[1];
  const float* wg = (const float*)d_in[2];
  const float* wu = (const float*)d_in[3];
  const float* wd = (const float*)d_in[4];
  float* out = (float*)d_out;
  char* ws = (char*)d_ws;

  // ws layout (bytes)
  int*   counts   = (int*)(ws + 0);          // 64
  int*   cursors  = (int*)(ws + 256);        // 64
  int*   offsets  = (int*)(ws + 512);        // 64
  int*   te       = (int*)(ws + 1024);       // 8192*2*4   = 64 KiB
  float* tw       = (float*)(ws + 66560);    // 64 KiB
  int*   tok_flat = (int*)(ws + 132096);     // 16384*4    = 64 KiB
  float* w_flat   = (float*)(ws + 197632);   // 64 KiB
  unsigned short* Xb  = (unsigned short*)(ws + 263168);     // 32 MiB
  unsigned short* Wgb = (unsigned short*)(ws + 33817600);   // 48 MiB
  unsigned short* Wub = (unsigned short*)(ws + 84149248);   // 48 MiB
  unsigned short* Wdb = (unsigned short*)(ws + 134480896);  // 48 MiB
  unsigned short* Hf  = (unsigned short*)(ws + 184812544);  // 24 MiB  -> end ~200 MiB

  hipMemsetAsync(counts, 0, 256, stream);
  hipMemsetAsync(d_out, 0, (size_t)NTOK * HID * sizeof(float), stream);

  cvt_kernel<<<2048, 256, 0, stream>>>(x,  Xb,  NTOK * HID);
  cvt_kernel<<<2048, 256, 0, stream>>>(wg, Wgb, NEXP * INTER * HID);
  cvt_kernel<<<2048, 256, 0, stream>>>(wu, Wub, NEXP * INTER * HID);
  cvt_kernel<<<2048, 256, 0, stream>>>(wd, Wdb, NEXP * HID * INTER);

  router_kernel<<<NTOK / 4, 256, 0, stream>>>(x, gw, counts, te, tw);
  scan_kernel<<<1, 64, 0, stream>>>(counts, offsets, cursors);
  scatter_kernel<<<NTOK / 256, 256, 0, stream>>>(te, tw, cursors, tok_flat, w_flat);

  gemm1_kernel<<<dim3(INTER / 128, NTOK / 128, NEXP), 256, 0, stream>>>(
      Xb, Wgb, Wub, counts, offsets, tok_flat, Hf);
  gemm2_kernel<<<dim3(HID / 128, NTOK / 128, NEXP), 256, 0, stream>>>(
      Hf, Wdb, counts, offsets, tok_flat, w_flat, out);
}

// Round 2
// 759.361 us; speedup vs baseline: 1.1548x; 1.1548x over previous
//
#include <hip/hip_runtime.h>
#include <hip/hip_bf16.h>

#define NTOK 8192
#define HID 2048
#define INTER 768
#define NEXP 16

typedef __bf16 bf16x8 __attribute__((ext_vector_type(8)));
typedef float f32x4 __attribute__((ext_vector_type(4)));

typedef const __attribute__((address_space(1))) void gvoid_t;
typedef __attribute__((address_space(3))) void lvoid_t;

static __device__ __forceinline__ void load_lds16(const void* g, void* l) {
  __builtin_amdgcn_global_load_lds((gvoid_t*)g, (lvoid_t*)l, 16, 0, 0);
}

static __device__ __forceinline__ unsigned short f2bf(float f) {
  unsigned int u = __float_as_uint(f);
  u += 0x7FFFu + ((u >> 16) & 1u);
  return (unsigned short)(u >> 16);
}

// ---------------- fp32 -> bf16 conversion (weights) ----------------
__global__ __launch_bounds__(256) void cvt_kernel(const float* __restrict__ src,
                                                  unsigned short* __restrict__ dst, int n) {
  int i = (blockIdx.x * 256 + threadIdx.x) * 4;
  int stride = gridDim.x * 256 * 4;
  for (; i < n; i += stride) {
    float4 v = *reinterpret_cast<const float4*>(src + i);
    ushort4 o;
    o.x = f2bf(v.x); o.y = f2bf(v.y); o.z = f2bf(v.z); o.w = f2bf(v.w);
    *reinterpret_cast<ushort4*>(dst + i) = o;
  }
}

// ---------------- router: logits (gw staged in LDS) + top2 + x->bf16 ----------------
__global__ __launch_bounds__(256) void router_kernel(const float* __restrict__ x,
                                                     const float* __restrict__ gw,
                                                     int* __restrict__ counts,
                                                     int* __restrict__ te,
                                                     float* __restrict__ tw,
                                                     unsigned short* __restrict__ Xb) {
  __shared__ float gws[NEXP][256];
  const int tid = threadIdx.x;
  const int lane = tid & 63;
  const int wid = tid >> 6;
  const int t = blockIdx.x * 4 + wid;
  const float* xp = x + (size_t)t * HID;
  unsigned short* xbp = Xb + (size_t)t * HID;

  float acc[NEXP];
#pragma unroll
  for (int e = 0; e < NEXP; ++e) acc[e] = 0.f;

  for (int c0 = 0; c0 < HID; c0 += 256) {
    // cooperative stage of gw chunk: 16 experts x 256 cols
#pragma unroll
    for (int r = 0; r < 4; ++r) {
      int idx = r * 1024 + tid * 4;
      int e = idx >> 8, c = idx & 255;
      *reinterpret_cast<float4*>(&gws[e][c]) =
          *reinterpret_cast<const float4*>(&gw[(size_t)e * HID + c0 + c]);
    }
    __syncthreads();
    float4 xv = *reinterpret_cast<const float4*>(&xp[c0 + lane * 4]);
    ushort4 o;
    o.x = f2bf(xv.x); o.y = f2bf(xv.y); o.z = f2bf(xv.z); o.w = f2bf(xv.w);
    *reinterpret_cast<ushort4*>(&xbp[c0 + lane * 4]) = o;
#pragma unroll
    for (int e = 0; e < NEXP; ++e) {
      float4 g4 = *reinterpret_cast<const float4*>(&gws[e][lane * 4]);
      acc[e] += xv.x * g4.x + xv.y * g4.y + xv.z * g4.z + xv.w * g4.w;
    }
    __syncthreads();
  }
#pragma unroll
  for (int e = 0; e < NEXP; ++e) {
#pragma unroll
    for (int m = 32; m >= 1; m >>= 1) acc[e] += __shfl_xor(acc[e], m);
  }
  if (lane == 0) {
    float b0 = -1e30f; int i0 = 0;
#pragma unroll
    for (int e = 0; e < NEXP; ++e) { if (acc[e] > b0) { b0 = acc[e]; i0 = e; } }
    float b1 = -1e30f; int i1 = 0;
#pragma unroll
    for (int e = 0; e < NEXP; ++e) { if (e != i0 && acc[e] > b1) { b1 = acc[e]; i1 = e; } }
    float w0 = 1.f / (1.f + __expf(b1 - b0));
    te[2 * t] = i0; te[2 * t + 1] = i1;
    tw[2 * t] = w0; tw[2 * t + 1] = 1.f - w0;
    atomicAdd(&counts[i0], 1);
    atomicAdd(&counts[i1], 1);
  }
}

// ---------------- prefix scan + compact tile worklist ----------------
__global__ void scan_kernel(const int* __restrict__ counts, int* __restrict__ offsets,
                            int* __restrict__ cursors, int* __restrict__ tile_map,
                            int* __restrict__ n_tiles) {
  int run = 0, nt = 0;
  for (int e = 0; e < NEXP; ++e) {
    offsets[e] = run; cursors[e] = run;
    int c = counts[e];
    for (int m0 = 0; m0 < c; m0 += 128) tile_map[nt++] = (e << 16) | m0;
    run += c;
  }
  *n_tiles = nt;
}

// ---------------- scatter tokens into per-expert flat lists ----------------
__global__ __launch_bounds__(256) void scatter_kernel(const int* __restrict__ te,
                                                      const float* __restrict__ tw,
                                                      int* __restrict__ cursors,
                                                      int* __restrict__ tok_flat,
                                                      float* __restrict__ w_flat) {
  int t = blockIdx.x * 256 + threadIdx.x;
  if (t >= NTOK) return;
#pragma unroll
  for (int k = 0; k < 2; ++k) {
    int e = te[2 * t + k];
    int pos = atomicAdd(&cursors[e], 1);
    tok_flat[pos] = t;
    w_flat[pos] = tw[2 * t + k];
  }
}

// Swizzle scheme (rule-21 compliant): LDS tile [128 rows][32 bf16 cols] = 64B rows
// of four 16B slots. LDS dest of global_load_lds is LINEAR (base + lane*16).
// Global SOURCE slot is permuted: src_slot = s ^ ((row>>1)&3). ds_read applies the
// same XOR -> each 16-lane fragment group spreads uniformly over all 8 bank-quads.

// ---------------- gemm1: H = silu(X Wg^T) * (X Wu^T), gathered rows ----------------
__global__ __launch_bounds__(256) void gemm1_kernel(
    const unsigned short* __restrict__ Xb,   // [NTOK][HID] bf16
    const unsigned short* __restrict__ Wg,   // [NEXP][INTER][HID] bf16
    const unsigned short* __restrict__ Wu,
    const int* __restrict__ counts, const int* __restrict__ offsets,
    const int* __restrict__ tok_flat,
    const int* __restrict__ tile_map, const int* __restrict__ n_tiles,
    unsigned short* __restrict__ Hf) {       // [2*NTOK][INTER] bf16
  // XCD-chunked bijective swizzle: nwg=864, 108 per XCD
  const int bid = blockIdx.x;
  const int wg = (bid & 7) * 108 + (bid >> 3);
  const int y = wg / 6;
  if (y >= *n_tiles) return;
  const int xb = wg - y * 6;
  const int tm = tile_map[y];
  const int e = tm >> 16, m0 = tm & 0xFFFF;
  const int cnt = counts[e];
  const int off = offsets[e];
  const int n0 = xb * 128;

  __shared__ __align__(16) unsigned short As0[128 * 32], As1[128 * 32];
  __shared__ __align__(16) unsigned short Bg0[128 * 32], Bg1[128 * 32];
  __shared__ __align__(16) unsigned short Bu0[128 * 32], Bu1[128 * 32];

  const int tid = threadIdx.x;
  const int lane = tid & 63;
  const int wid = tid >> 6;
  const int rl = tid >> 2;              // staging row 0..63 (+64 for it=1)
  const int srcc = ((tid & 3) ^ ((tid >> 3) & 3)) * 8;  // swizzled global slot
  const int d0 = tid * 8;               // ushort idx; byte = tid*16 (linear)
  const int d1 = d0 + 64 * 32;

  int r0 = m0 + rl, r1 = m0 + 64 + rl;
  int s0 = (r0 < cnt) ? off + r0 : off;
  int s1 = (r1 < cnt) ? off + r1 : off;
  const unsigned short* xsrc0 = Xb + (size_t)tok_flat[s0] * HID + srcc;
  const unsigned short* xsrc1 = Xb + (size_t)tok_flat[s1] * HID + srcc;
  const unsigned short* gsrc0 = Wg + ((size_t)e * INTER + n0 + rl) * HID + srcc;
  const unsigned short* gsrc1 = gsrc0 + (size_t)64 * HID;
  const unsigned short* usrc0 = Wu + ((size_t)e * INTER + n0 + rl) * HID + srcc;
  const unsigned short* usrc1 = usrc0 + (size_t)64 * HID;

  f32x4 zero = {0.f, 0.f, 0.f, 0.f};
  f32x4 accG[4][4], accU[4][4];
#pragma unroll
  for (int i = 0; i < 4; ++i)
#pragma unroll
    for (int j = 0; j < 4; ++j) { accG[i][j] = zero; accU[i][j] = zero; }

  const int wm = (wid >> 1) * 64;
  const int wn = (wid & 1) * 64;
  const int fr = lane & 15;
  const int cs = (((lane >> 4) ^ ((lane >> 1) & 3)) * 8);  // swizzled read slot

#define STAGE1(AS, BGS, BUS, kt)                    \
  {                                                 \
    load_lds16(xsrc0 + (kt), (AS) + d0);            \
    load_lds16(xsrc1 + (kt), (AS) + d1);            \
    load_lds16(gsrc0 + (kt), (BGS) + d0);           \
    load_lds16(gsrc1 + (kt), (BGS) + d1);           \
    load_lds16(usrc0 + (kt), (BUS) + d0);           \
    load_lds16(usrc1 + (kt), (BUS) + d1);           \
  }

#define COMPUTE1(AS, BGS, BUS)                                                         \
  {                                                                                    \
    bf16x8 af[4], bg[4], bu[4];                                                        \
    _Pragma("unroll") for (int i = 0; i < 4; ++i) {                                    \
      af[i] = *reinterpret_cast<const bf16x8*>((AS) + (wm + i * 16 + fr) * 32 + cs);   \
      bg[i] = *reinterpret_cast<const bf16x8*>((BGS) + (wn + i * 16 + fr) * 32 + cs);  \
      bu[i] = *reinterpret_cast<const bf16x8*>((BUS) + (wn + i * 16 + fr) * 32 + cs);  \
    }                                                                                  \
    _Pragma("unroll") for (int i = 0; i < 4; ++i)                                      \
      _Pragma("unroll") for (int j = 0; j < 4; ++j) {                                  \
        accG[i][j] = __builtin_amdgcn_mfma_f32_16x16x32_bf16(af[i], bg[j], accG[i][j], 0, 0, 0); \
        accU[i][j] = __builtin_amdgcn_mfma_f32_16x16x32_bf16(af[i], bu[j], accU[i][j], 0, 0, 0); \
      }                                                                                \
  }

  STAGE1(As0, Bg0, Bu0, 0);
  __syncthreads();
#pragma unroll 1
  for (int kt = 0; kt < HID; kt += 64) {
    STAGE1(As1, Bg1, Bu1, kt + 32);
    COMPUTE1(As0, Bg0, Bu0);
    __syncthreads();
    if (kt + 64 < HID) STAGE1(As0, Bg0, Bu0, kt + 64);
    COMPUTE1(As1, Bg1, Bu1);
    __syncthreads();
  }
#undef STAGE1
#undef COMPUTE1

  const int lr = (lane >> 4) * 4;
  const int lc = lane & 15;
#pragma unroll
  for (int i = 0; i < 4; ++i) {
#pragma unroll
    for (int r = 0; r < 4; ++r) {
      int m = wm + i * 16 + lr + r;
      if (m0 + m < cnt) {
        size_t base = (size_t)(off + m0 + m) * INTER + (size_t)(n0 + wn + lc);
#pragma unroll
        for (int j = 0; j < 4; ++j) {
          float g = accG[i][j][r];
          float u = accU[i][j][r];
          float h = g / (1.f + __expf(-g)) * u;
          Hf[base + j * 16] = f2bf(h);
        }
      }
    }
  }
}

// ---------------- gemm2: out[t] += w * (H Wd^T) ----------------
__global__ __launch_bounds__(256) void gemm2_kernel(
    const unsigned short* __restrict__ Hf,   // [2*NTOK][INTER] bf16
    const unsigned short* __restrict__ Wd,   // [NEXP][HID][INTER] bf16
    const int* __restrict__ counts, const int* __restrict__ offsets,
    const int* __restrict__ tok_flat, const float* __restrict__ w_flat,
    const int* __restrict__ tile_map, const int* __restrict__ n_tiles,
    float* __restrict__ out) {
  // nwg = 2304, 288 per XCD
  const int bid = blockIdx.x;
  const int wg = (bid & 7) * 288 + (bid >> 3);
  const int y = wg / 16;
  if (y >= *n_tiles) return;
  const int xb = wg - y * 16;
  const int tm = tile_map[y];
  const int e = tm >> 16, m0 = tm & 0xFFFF;
  const int cnt = counts[e];
  const int off = offsets[e];
  const int n0 = xb * 128;

  __shared__ __align__(16) unsigned short As0[128 * 32], As1[128 * 32];
  __shared__ __align__(16) unsigned short Bs0[128 * 32], Bs1[128 * 32];

  const int tid = threadIdx.x;
  const int lane = tid & 63;
  const int wid = tid >> 6;
  const int rl = tid >> 2;
  const int srcc = ((tid & 3) ^ ((tid >> 3) & 3)) * 8;
  const int d0 = tid * 8;
  const int d1 = d0 + 64 * 32;

  int r0 = m0 + rl, r1 = m0 + 64 + rl;
  int sa0 = (r0 < cnt) ? off + r0 : off;
  int sa1 = (r1 < cnt) ? off + r1 : off;
  const unsigned short* asrc0 = Hf + (size_t)sa0 * INTER + srcc;
  const unsigned short* asrc1 = Hf + (size_t)sa1 * INTER + srcc;
  const unsigned short* bsrc0 = Wd + ((size_t)e * HID + n0 + rl) * INTER + srcc;
  const unsigned short* bsrc1 = bsrc0 + (size_t)64 * INTER;

  f32x4 zero = {0.f, 0.f, 0.f, 0.f};
  f32x4 acc[4][4];
#pragma unroll
  for (int i = 0; i < 4; ++i)
#pragma unroll
    for (int j = 0; j < 4; ++j) acc[i][j] = zero;

  const int wm = (wid >> 1) * 64;
  const int wn = (wid & 1) * 64;
  const int fr = lane & 15;
  const int cs = (((lane >> 4) ^ ((lane >> 1) & 3)) * 8);

#define STAGE2(AS, BS, kt)                          \
  {                                                 \
    load_lds16(asrc0 + (kt), (AS) + d0);            \
    load_lds16(asrc1 + (kt), (AS) + d1);            \
    load_lds16(bsrc0 + (kt), (BS) + d0);            \
    load_lds16(bsrc1 + (kt), (BS) + d1);            \
  }

#define COMPUTE2(AS, BS)                                                               \
  {                                                                                    \
    bf16x8 af[4], bf_[4];                                                              \
    _Pragma("unroll") for (int i = 0; i < 4; ++i) {                                    \
      af[i] = *reinterpret_cast<const bf16x8*>((AS) + (wm + i * 16 + fr) * 32 + cs);   \
      bf_[i] = *reinterpret_cast<const bf16x8*>((BS) + (wn + i * 16 + fr) * 32 + cs);  \
    }                                                                                  \
    _Pragma("unroll") for (int i = 0; i < 4; ++i)                                      \
      _Pragma("unroll") for (int j = 0; j < 4; ++j)                                    \
        acc[i][j] = __builtin_amdgcn_mfma_f32_16x16x32_bf16(af[i], bf_[j], acc[i][j], 0, 0, 0); \
  }

  STAGE2(As0, Bs0, 0);
  __syncthreads();
#pragma unroll 1
  for (int kt = 0; kt < INTER; kt += 64) {
    STAGE2(As1, Bs1, kt + 32);
    COMPUTE2(As0, Bs0);
    __syncthreads();
    if (kt + 64 < INTER) STAGE2(As0, Bs0, kt + 64);
    COMPUTE2(As1, Bs1);
    __syncthreads();
  }
#undef STAGE2
#undef COMPUTE2

  const int lr = (lane >> 4) * 4;
  const int lc = lane & 15;
#pragma unroll
  for (int i = 0; i < 4; ++i) {
#pragma unroll
    for (int r = 0; r < 4; ++r) {
      int m = wm + i * 16 + lr + r;
      if (m0 + m < cnt) {
        int slot = off + m0 + m;
        int t = tok_flat[slot];
        float w = w_flat[slot];
        float* op = out + (size_t)t * HID + (size_t)(n0 + wn + lc);
#pragma unroll
        for (int j = 0; j < 4; ++j) {
          atomicAdd(op + j * 16, w * acc[i][j][r]);
        }
      }
    }
  }
}

// ---------------- launch ----------------
extern "C" void kernel_launch(void* const* d_in, const int* in_sizes, int n_in,
                              void* d_out, int out_size, void* d_ws, size_t ws_size,
                              hipStream_t stream) {
  const float* x  = (const float*)d_in[0];
  const float* gw = (const float*)d_in[1];
  const float* wg = (const float*)d_in[2];
  const float* wu = (const float*)d_in[3];
  const float* wd = (const float*)d_in[4];
  float* out = (float*)d_out;
  char* ws = (char*)d_ws;

  // ws layout (bytes)
  int*   counts   = (int*)(ws + 0);          // 64
  int*   cursors  = (int*)(ws + 64);         // 64
  int*   offsets  = (int*)(ws + 128);        // 64
  int*   n_tiles  = (int*)(ws + 192);        // 4
  int*   tile_map = (int*)(ws + 256);        // 144*4 = 576
  int*   te       = (int*)(ws + 1024);       // 64 KiB
  float* tw       = (float*)(ws + 66560);    // 64 KiB
  int*   tok_flat = (int*)(ws + 132096);     // 64 KiB
  float* w_flat   = (float*)(ws + 197632);   // 64 KiB
  unsigned short* Xb  = (unsigned short*)(ws + 263168);     // 32 MiB
  unsigned short* Wgb = (unsigned short*)(ws + 33817600);   // 48 MiB
  unsigned short* Wub = (unsigned short*)(ws + 84149248);   // 48 MiB
  unsigned short* Wdb = (unsigned short*)(ws + 134480896);  // 48 MiB
  unsigned short* Hf  = (unsigned short*)(ws + 184812544);  // 24 MiB

  hipMemsetAsync(counts, 0, 256, stream);
  hipMemsetAsync(d_out, 0, (size_t)NTOK * HID * sizeof(float), stream);

  cvt_kernel<<<2048, 256, 0, stream>>>(wg, Wgb, NEXP * INTER * HID);
  cvt_kernel<<<2048, 256, 0, stream>>>(wu, Wub, NEXP * INTER * HID);
  cvt_kernel<<<2048, 256, 0, stream>>>(wd, Wdb, NEXP * HID * INTER);

  router_kernel<<<NTOK / 4, 256, 0, stream>>>(x, gw, counts, te, tw, Xb);
  scan_kernel<<<1, 1, 0, stream>>>(counts, offsets, cursors, tile_map, n_tiles);
  scatter_kernel<<<NTOK / 256, 256, 0, stream>>>(te, tw, cursors, tok_flat, w_flat);

  gemm1_kernel<<<144 * 6, 256, 0, stream>>>(
      Xb, Wgb, Wub, counts, offsets, tok_flat, tile_map, n_tiles, Hf);
  gemm2_kernel<<<144 * 16, 256, 0, stream>>>(
      Hf, Wdb, counts, offsets, tok_flat, w_flat, tile_map, n_tiles, out);
}

// Round 3
// 684.058 us; speedup vs baseline: 1.2820x; 1.1101x over previous
//
#include <hip/hip_runtime.h>
#include <hip/hip_bf16.h>

#define NTOK 8192
#define HID 2048
#define INTER 768
#define NEXP 16

typedef __bf16 bf16x8 __attribute__((ext_vector_type(8)));
typedef float f32x4 __attribute__((ext_vector_type(4)));

typedef const __attribute__((address_space(1))) void gvoid_t;
typedef __attribute__((address_space(3))) void lvoid_t;

static __device__ __forceinline__ void load_lds16(const void* g, void* l) {
  __builtin_amdgcn_global_load_lds((gvoid_t*)g, (lvoid_t*)l, 16, 0, 0);
}

static __device__ __forceinline__ unsigned short f2bf(float f) {
  unsigned int u = __float_as_uint(f);
  u += 0x7FFFu + ((u >> 16) & 1u);
  return (unsigned short)(u >> 16);
}

static __device__ __forceinline__ float bf2f(unsigned short b) {
  return __uint_as_float(((unsigned int)b) << 16);
}

// ---------------- fp32 -> bf16 conversion (weights) ----------------
__global__ __launch_bounds__(256) void cvt_kernel(const float* __restrict__ src,
                                                  unsigned short* __restrict__ dst, int n) {
  int i = (blockIdx.x * 256 + threadIdx.x) * 4;
  int stride = gridDim.x * 256 * 4;
  for (; i < n; i += stride) {
    float4 v = *reinterpret_cast<const float4*>(src + i);
    ushort4 o;
    o.x = f2bf(v.x); o.y = f2bf(v.y); o.z = f2bf(v.z); o.w = f2bf(v.w);
    *reinterpret_cast<ushort4*>(dst + i) = o;
  }
}

// ---------------- router: logits (gw staged in LDS) + top2 + x->bf16 ----------------
__global__ __launch_bounds__(256) void router_kernel(const float* __restrict__ x,
                                                     const float* __restrict__ gw,
                                                     int* __restrict__ counts,
                                                     int* __restrict__ te,
                                                     float* __restrict__ tw,
                                                     unsigned short* __restrict__ Xb) {
  __shared__ float gws[NEXP][256];
  const int tid = threadIdx.x;
  const int lane = tid & 63;
  const int wid = tid >> 6;
  const int t = blockIdx.x * 4 + wid;
  const float* xp = x + (size_t)t * HID;
  unsigned short* xbp = Xb + (size_t)t * HID;

  float acc[NEXP];
#pragma unroll
  for (int e = 0; e < NEXP; ++e) acc[e] = 0.f;

  for (int c0 = 0; c0 < HID; c0 += 256) {
#pragma unroll
    for (int r = 0; r < 4; ++r) {
      int idx = r * 1024 + tid * 4;
      int e = idx >> 8, c = idx & 255;
      *reinterpret_cast<float4*>(&gws[e][c]) =
          *reinterpret_cast<const float4*>(&gw[(size_t)e * HID + c0 + c]);
    }
    __syncthreads();
    float4 xv = *reinterpret_cast<const float4*>(&xp[c0 + lane * 4]);
    ushort4 o;
    o.x = f2bf(xv.x); o.y = f2bf(xv.y); o.z = f2bf(xv.z); o.w = f2bf(xv.w);
    *reinterpret_cast<ushort4*>(&xbp[c0 + lane * 4]) = o;
#pragma unroll
    for (int e = 0; e < NEXP; ++e) {
      float4 g4 = *reinterpret_cast<const float4*>(&gws[e][lane * 4]);
      acc[e] += xv.x * g4.x + xv.y * g4.y + xv.z * g4.z + xv.w * g4.w;
    }
    __syncthreads();
  }
#pragma unroll
  for (int e = 0; e < NEXP; ++e) {
#pragma unroll
    for (int m = 32; m >= 1; m >>= 1) acc[e] += __shfl_xor(acc[e], m);
  }
  if (lane == 0) {
    float b0 = -1e30f; int i0 = 0;
#pragma unroll
    for (int e = 0; e < NEXP; ++e) { if (acc[e] > b0) { b0 = acc[e]; i0 = e; } }
    float b1 = -1e30f; int i1 = 0;
#pragma unroll
    for (int e = 0; e < NEXP; ++e) { if (e != i0 && acc[e] > b1) { b1 = acc[e]; i1 = e; } }
    float w0 = 1.f / (1.f + __expf(b1 - b0));
    te[2 * t] = i0; te[2 * t + 1] = i1;
    tw[2 * t] = w0; tw[2 * t + 1] = 1.f - w0;
    atomicAdd(&counts[i0], 1);
    atomicAdd(&counts[i1], 1);
  }
}

// ---------------- prefix scan + compact tile worklist ----------------
__global__ void scan_kernel(const int* __restrict__ counts, int* __restrict__ offsets,
                            int* __restrict__ cursors, int* __restrict__ tile_map,
                            int* __restrict__ n_tiles) {
  int run = 0, nt = 0;
  for (int e = 0; e < NEXP; ++e) {
    offsets[e] = run; cursors[e] = run;
    int c = counts[e];
    for (int m0 = 0; m0 < c; m0 += 128) tile_map[nt++] = (e << 16) | m0;
    run += c;
  }
  *n_tiles = nt;
}

// ---------------- scatter tokens into per-expert flat lists ----------------
__global__ __launch_bounds__(256) void scatter_kernel(const int* __restrict__ te,
                                                      const float* __restrict__ tw,
                                                      int* __restrict__ cursors,
                                                      int* __restrict__ tok_flat,
                                                      float* __restrict__ w_flat) {
  int t = blockIdx.x * 256 + threadIdx.x;
  if (t >= NTOK) return;
#pragma unroll
  for (int k = 0; k < 2; ++k) {
    int e = te[2 * t + k];
    int pos = atomicAdd(&cursors[e], 1);
    tok_flat[pos] = t;
    w_flat[pos] = tw[2 * t + k];
  }
}

// Epilogue modes
#define EP_G 0  // write raw gate-proj (bf16) to Hf
#define EP_U 1  // read g from Hf, write silu(g)*u to Hf
#define EP_D 2  // weighted atomicAdd into fp32 out

// Unified GEMM: BM=128, BN=128, BK=32 double-buffered, 4 waves 2x2 (wave tile
// 64x64 -> 16 f32x4 acc). LDS slot-XOR swizzle (rule-21: linear LDS dest,
// permuted GLOBAL source slot, same XOR on ds_read) -> zero bank conflicts
// (verified round 2). XCD-chunk swizzle on blockIdx (grid % 8 == 0).
template <int MODE, int NXB, int KD>
__global__ __launch_bounds__(256, 3) void gemm_kernel(
    const unsigned short* __restrict__ A,    // Xb (G/U) or Hf (D)
    const unsigned short* __restrict__ Bw,   // weights [E][NXB*128][KD] bf16
    const int* __restrict__ counts, const int* __restrict__ offsets,
    const int* __restrict__ tok_flat, const float* __restrict__ w_flat,
    const int* __restrict__ tile_map, const int* __restrict__ n_tiles,
    unsigned short* __restrict__ Hf, float* __restrict__ out) {
  const int bid = blockIdx.x;
  const int cpx = gridDim.x >> 3;
  const int wg = (bid & 7) * cpx + (bid >> 3);
  const int y = wg / NXB;
  if (y >= *n_tiles) return;
  const int xb = wg - y * NXB;
  const int tm = tile_map[y];
  const int e = tm >> 16, m0 = tm & 0xFFFF;
  const int cnt = counts[e];
  const int off = offsets[e];
  const int n0 = xb * 128;

  __shared__ __align__(16) unsigned short As0[128 * 32], As1[128 * 32];
  __shared__ __align__(16) unsigned short Bs0[128 * 32], Bs1[128 * 32];

  const int tid = threadIdx.x;
  const int lane = tid & 63;
  const int wid = tid >> 6;
  const int rl = tid >> 2;                              // staging row 0..63
  const int srcc = ((tid & 3) ^ ((tid >> 3) & 3)) * 8;  // swizzled global slot
  const int d0 = tid * 8;                               // linear LDS dest (ushort idx)
  const int d1 = d0 + 64 * 32;

  const int r0 = m0 + rl, r1 = r0 + 64;
  const int s0 = (r0 < cnt) ? off + r0 : off;
  const int s1 = (r1 < cnt) ? off + r1 : off;
  const unsigned short* aptr0;
  const unsigned short* aptr1;
  if (MODE == EP_D) {
    aptr0 = A + (size_t)s0 * KD + srcc;
    aptr1 = A + (size_t)s1 * KD + srcc;
  } else {
    aptr0 = A + (size_t)tok_flat[s0] * KD + srcc;
    aptr1 = A + (size_t)tok_flat[s1] * KD + srcc;
  }
  const unsigned short* bptr0 = Bw + ((size_t)e * (NXB * 128) + n0 + rl) * KD + srcc;
  const unsigned short* bptr1 = bptr0 + (size_t)64 * KD;

  f32x4 zero = {0.f, 0.f, 0.f, 0.f};
  f32x4 acc[4][4];
#pragma unroll
  for (int i = 0; i < 4; ++i)
#pragma unroll
    for (int j = 0; j < 4; ++j) acc[i][j] = zero;

  const int wm = (wid >> 1) * 64;
  const int wn = (wid & 1) * 64;
  const int fr = lane & 15;
  const int cs = (((lane >> 4) ^ ((lane >> 1) & 3)) * 8);  // swizzled read slot

#define STAGE(AS, BS, kt)                 \
  {                                       \
    load_lds16(aptr0 + (kt), (AS) + d0);  \
    load_lds16(aptr1 + (kt), (AS) + d1);  \
    load_lds16(bptr0 + (kt), (BS) + d0);  \
    load_lds16(bptr1 + (kt), (BS) + d1);  \
  }

#define COMPUTE(AS, BS)                                                                \
  {                                                                                    \
    bf16x8 af[4], bf_[4];                                                              \
    _Pragma("unroll") for (int i = 0; i < 4; ++i) {                                    \
      af[i] = *reinterpret_cast<const bf16x8*>((AS) + (wm + i * 16 + fr) * 32 + cs);   \
      bf_[i] = *reinterpret_cast<const bf16x8*>((BS) + (wn + i * 16 + fr) * 32 + cs);  \
    }                                                                                  \
    _Pragma("unroll") for (int i = 0; i < 4; ++i)                                      \
      _Pragma("unroll") for (int j = 0; j < 4; ++j)                                    \
        acc[i][j] = __builtin_amdgcn_mfma_f32_16x16x32_bf16(af[i], bf_[j], acc[i][j], 0, 0, 0); \
  }

  STAGE(As0, Bs0, 0);
  __syncthreads();
#pragma unroll 1
  for (int kt = 0; kt < KD; kt += 64) {
    STAGE(As1, Bs1, kt + 32);
    COMPUTE(As0, Bs0);
    __syncthreads();
    if (kt + 64 < KD) STAGE(As0, Bs0, kt + 64);
    COMPUTE(As1, Bs1);
    __syncthreads();
  }
#undef STAGE
#undef COMPUTE

  const int lr = (lane >> 4) * 4;
  const int lc = lane & 15;
#pragma unroll
  for (int i = 0; i < 4; ++i) {
#pragma unroll
    for (int r = 0; r < 4; ++r) {
      int m = wm + i * 16 + lr + r;
      if (m0 + m < cnt) {
        int slot = off + m0 + m;
        if (MODE == EP_G) {
          size_t base = (size_t)slot * INTER + (size_t)(n0 + wn + lc);
#pragma unroll
          for (int j = 0; j < 4; ++j) Hf[base + j * 16] = f2bf(acc[i][j][r]);
        } else if (MODE == EP_U) {
          size_t base = (size_t)slot * INTER + (size_t)(n0 + wn + lc);
#pragma unroll
          for (int j = 0; j < 4; ++j) {
            float g = bf2f(Hf[base + j * 16]);
            float u = acc[i][j][r];
            float h = g / (1.f + __expf(-g)) * u;
            Hf[base + j * 16] = f2bf(h);
          }
        } else {
          int t = tok_flat[slot];
          float w = w_flat[slot];
          float* op = out + (size_t)t * HID + (size_t)(n0 + wn + lc);
#pragma unroll
          for (int j = 0; j < 4; ++j) atomicAdd(op + j * 16, w * acc[i][j][r]);
        }
      }
    }
  }
}

// ---------------- launch ----------------
extern "C" void kernel_launch(void* const* d_in, const int* in_sizes, int n_in,
                              void* d_out, int out_size, void* d_ws, size_t ws_size,
                              hipStream_t stream) {
  const float* x  = (const float*)d_in[0];
  const float* gw = (const float*)d_in[1];
  const float* wg = (const float*)d_in[2];
  const float* wu = (const float*)d_in[3];
  const float* wd = (const float*)d_in[4];
  float* out = (float*)d_out;
  char* ws = (char*)d_ws;

  // ws layout (bytes)
  int*   counts   = (int*)(ws + 0);          // 64
  int*   cursors  = (int*)(ws + 64);         // 64
  int*   offsets  = (int*)(ws + 128);        // 64
  int*   n_tiles  = (int*)(ws + 192);        // 4
  int*   tile_map = (int*)(ws + 256);        // 144*4
  int*   te       = (int*)(ws + 1024);       // 64 KiB
  float* tw       = (float*)(ws + 66560);    // 64 KiB
  int*   tok_flat = (int*)(ws + 132096);     // 64 KiB
  float* w_flat   = (float*)(ws + 197632);   // 64 KiB
  unsigned short* Xb  = (unsigned short*)(ws + 263168);     // 32 MiB
  unsigned short* Wgb = (unsigned short*)(ws + 33817600);   // 48 MiB
  unsigned short* Wub = (unsigned short*)(ws + 84149248);   // 48 MiB
  unsigned short* Wdb = (unsigned short*)(ws + 134480896);  // 48 MiB
  unsigned short* Hf  = (unsigned short*)(ws + 184812544);  // 24 MiB

  hipMemsetAsync(counts, 0, 256, stream);
  hipMemsetAsync(d_out, 0, (size_t)NTOK * HID * sizeof(float), stream);

  cvt_kernel<<<2048, 256, 0, stream>>>(wg, Wgb, NEXP * INTER * HID);
  cvt_kernel<<<2048, 256, 0, stream>>>(wu, Wub, NEXP * INTER * HID);
  cvt_kernel<<<2048, 256, 0, stream>>>(wd, Wdb, NEXP * HID * INTER);

  router_kernel<<<NTOK / 4, 256, 0, stream>>>(x, gw, counts, te, tw, Xb);
  scan_kernel<<<1, 1, 0, stream>>>(counts, offsets, cursors, tile_map, n_tiles);
  scatter_kernel<<<NTOK / 256, 256, 0, stream>>>(te, tw, cursors, tok_flat, w_flat);

  gemm_kernel<EP_G, 6, HID><<<144 * 6, 256, 0, stream>>>(
      Xb, Wgb, counts, offsets, tok_flat, w_flat, tile_map, n_tiles, Hf, out);
  gemm_kernel<EP_U, 6, HID><<<144 * 6, 256, 0, stream>>>(
      Xb, Wub, counts, offsets, tok_flat, w_flat, tile_map, n_tiles, Hf, out);
  gemm_kernel<EP_D, 16, INTER><<<144 * 16, 256, 0, stream>>>(
      Hf, Wdb, counts, offsets, tok_flat, w_flat, tile_map, n_tiles, Hf, out);
}

// Round 4
// 516.269 us; speedup vs baseline: 1.6986x; 1.3250x over previous
//
#include <hip/hip_runtime.h>
#include <hip/hip_bf16.h>

#define NTOK 8192
#define HID 2048
#define INTER 768
#define NEXP 16

typedef __bf16 bf16x8 __attribute__((ext_vector_type(8)));
typedef float f32x4 __attribute__((ext_vector_type(4)));

typedef const __attribute__((address_space(1))) void gvoid_t;
typedef __attribute__((address_space(3))) void lvoid_t;

static __device__ __forceinline__ void load_lds16(const void* g, void* l) {
  __builtin_amdgcn_global_load_lds((gvoid_t*)g, (lvoid_t*)l, 16, 0, 0);
}

static __device__ __forceinline__ unsigned short f2bf(float f) {
  unsigned int u = __float_as_uint(f);
  u += 0x7FFFu + ((u >> 16) & 1u);
  return (unsigned short)(u >> 16);
}

static __device__ __forceinline__ float bf2f(unsigned short b) {
  return __uint_as_float(((unsigned int)b) << 16);
}

// ---------------- fp32 -> bf16 conversion (weights) ----------------
__global__ __launch_bounds__(256) void cvt_kernel(const float* __restrict__ src,
                                                  unsigned short* __restrict__ dst, int n) {
  int i = (blockIdx.x * 256 + threadIdx.x) * 4;
  int stride = gridDim.x * 256 * 4;
  for (; i < n; i += stride) {
    float4 v = *reinterpret_cast<const float4*>(src + i);
    ushort4 o;
    o.x = f2bf(v.x); o.y = f2bf(v.y); o.z = f2bf(v.z); o.w = f2bf(v.w);
    *reinterpret_cast<ushort4*>(dst + i) = o;
  }
}

// ---------------- router: barrier-free, LDS-free, atomic-free ----------------
// 2 tokens per wave; x rows in registers; gw streamed from L2 (hot, 128 KB).
__global__ __launch_bounds__(256) void router_kernel(const float* __restrict__ x,
                                                     const float* __restrict__ gw,
                                                     int* __restrict__ te,
                                                     float* __restrict__ tw,
                                                     unsigned short* __restrict__ Xb) {
  const int lane = threadIdx.x & 63;
  const int wid = threadIdx.x >> 6;
  const int t0 = (blockIdx.x * 4 + wid) * 2;  // this wave's two tokens
  const float4* xa = reinterpret_cast<const float4*>(x + (size_t)t0 * HID);
  const float4* xb = xa + HID / 4;
  const float4* g4 = reinterpret_cast<const float4*>(gw);

  float4 va[8], vb[8];
#pragma unroll
  for (int j = 0; j < 8; ++j) {
    va[j] = xa[lane + 64 * j];
    vb[j] = xb[lane + 64 * j];
  }
  // fold x -> bf16 conversion (coalesced ushort4 stores)
  ushort4* oa = reinterpret_cast<ushort4*>(Xb + (size_t)t0 * HID);
  ushort4* ob = oa + HID / 4;
#pragma unroll
  for (int j = 0; j < 8; ++j) {
    ushort4 u;
    u.x = f2bf(va[j].x); u.y = f2bf(va[j].y); u.z = f2bf(va[j].z); u.w = f2bf(va[j].w);
    oa[lane + 64 * j] = u;
    u.x = f2bf(vb[j].x); u.y = f2bf(vb[j].y); u.z = f2bf(vb[j].z); u.w = f2bf(vb[j].w);
    ob[lane + 64 * j] = u;
  }

  float accA[NEXP], accB[NEXP];
#pragma unroll
  for (int e = 0; e < NEXP; ++e) { accA[e] = 0.f; accB[e] = 0.f; }
#pragma unroll
  for (int e = 0; e < NEXP; ++e) {
#pragma unroll
    for (int j = 0; j < 8; ++j) {
      float4 g = g4[e * (HID / 4) + lane + 64 * j];
      accA[e] += va[j].x * g.x + va[j].y * g.y + va[j].z * g.z + va[j].w * g.w;
      accB[e] += vb[j].x * g.x + vb[j].y * g.y + vb[j].z * g.z + vb[j].w * g.w;
    }
  }
#pragma unroll
  for (int e = 0; e < NEXP; ++e) {
#pragma unroll
    for (int m = 32; m >= 1; m >>= 1) {
      accA[e] += __shfl_xor(accA[e], m);
      accB[e] += __shfl_xor(accB[e], m);
    }
  }
  if (lane == 0) {
#pragma unroll
    for (int k = 0; k < 2; ++k) {
      const float* acc = k ? accB : accA;
      int t = t0 + k;
      float b0 = -1e30f; int i0 = 0;
#pragma unroll
      for (int e = 0; e < NEXP; ++e) { if (acc[e] > b0) { b0 = acc[e]; i0 = e; } }
      float b1 = -1e30f; int i1 = 0;
#pragma unroll
      for (int e = 0; e < NEXP; ++e) { if (e != i0 && acc[e] > b1) { b1 = acc[e]; i1 = e; } }
      float w0 = 1.f / (1.f + __expf(b1 - b0));
      te[2 * t] = i0; te[2 * t + 1] = i1;
      tw[2 * t] = w0; tw[2 * t + 1] = 1.f - w0;
    }
  }
}

// ---------------- build: histogram + scan + scatter, ONE block, NO atomics ----------------
__global__ __launch_bounds__(256) void build_kernel(
    const int* __restrict__ te, const float* __restrict__ tw,
    int* __restrict__ counts, int* __restrict__ offsets,
    int* __restrict__ tok_flat, float* __restrict__ w_flat,
    int* __restrict__ tile_map, int* __restrict__ n_tiles) {
  __shared__ int lds_cnt[NEXP][257];  // [ex][tid] per-thread counts -> exclusive scan; [ex][256]=total
  __shared__ int lds_off[NEXP];
  const int tid = threadIdx.x;
  const int lane = tid & 63;
  const int wv = tid >> 6;

  // pass 1: per-thread 16-bin histogram of entries [tid*64, tid*64+64)
  int cnt[NEXP];
#pragma unroll
  for (int ex = 0; ex < NEXP; ++ex) cnt[ex] = 0;
  for (int i = 0; i < 64; ++i) {
    int e = te[tid * 64 + i];
#pragma unroll
    for (int ex = 0; ex < NEXP; ++ex) cnt[ex] += (e == ex) ? 1 : 0;
  }
#pragma unroll
  for (int ex = 0; ex < NEXP; ++ex) lds_cnt[ex][tid] = cnt[ex];
  __syncthreads();

  // per-expert exclusive scan across 256 threads (wave wv owns experts 4wv..4wv+3)
  for (int ex = wv * 4; ex < wv * 4 + 4; ++ex) {
    int carry = 0;
    for (int c = 0; c < 4; ++c) {
      int v = lds_cnt[ex][c * 64 + lane];
      int s = v;
#pragma unroll
      for (int d = 1; d < 64; d <<= 1) {
        int o = __shfl_up(s, d);
        if (lane >= d) s += o;
      }
      lds_cnt[ex][c * 64 + lane] = carry + s - v;  // exclusive
      carry += __shfl(s, 63);
    }
    if (lane == 0) lds_cnt[ex][256] = carry;  // total for expert ex
  }
  __syncthreads();

  if (tid == 0) {
    int run = 0, nt = 0;
    for (int e = 0; e < NEXP; ++e) {
      int tot = lds_cnt[e][256];
      counts[e] = tot;
      offsets[e] = run;
      lds_off[e] = run;
      for (int m0 = 0; m0 < tot; m0 += 128) tile_map[nt++] = (e << 16) | m0;
      run += tot;
    }
    *n_tiles = nt;
  }
  __syncthreads();

  // pass 2: place entries; pure register cursors (static-unrolled bins)
  int base[NEXP];
#pragma unroll
  for (int ex = 0; ex < NEXP; ++ex) base[ex] = lds_off[ex] + lds_cnt[ex][tid];
  for (int i = 0; i < 64; ++i) {
    int idx = tid * 64 + i;
    int e = te[idx];
    float w = tw[idx];
    int pos = 0;
#pragma unroll
    for (int ex = 0; ex < NEXP; ++ex) {
      if (e == ex) { pos = base[ex]; base[ex] = pos + 1; }
    }
    tok_flat[pos] = idx >> 1;
    w_flat[pos] = w;
  }
}

// Epilogue modes
#define EP_G 0  // write raw gate-proj (bf16) to Hf
#define EP_U 1  // read g from Hf, write silu(g)*u to Hf
#define EP_D 2  // weighted atomicAdd into fp32 out

// Unified GEMM: BM=128, BN=128, BK=32 double-buffered, 4 waves 2x2.
// LDS slot-XOR swizzle (linear LDS dest, permuted GLOBAL source slot, same XOR
// on ds_read) -> zero bank conflicts (verified). XCD-chunk blockIdx swizzle.
template <int MODE, int NXB, int KD>
__global__ __launch_bounds__(256, 3) void gemm_kernel(
    const unsigned short* __restrict__ A,    // Xb (G/U) or Hf (D)
    const unsigned short* __restrict__ Bw,   // weights [E][NXB*128][KD] bf16
    const int* __restrict__ counts, const int* __restrict__ offsets,
    const int* __restrict__ tok_flat, const float* __restrict__ w_flat,
    const int* __restrict__ tile_map, const int* __restrict__ n_tiles,
    unsigned short* __restrict__ Hf, float* __restrict__ out) {
  const int bid = blockIdx.x;
  const int cpx = gridDim.x >> 3;
  const int wg = (bid & 7) * cpx + (bid >> 3);
  const int y = wg / NXB;
  if (y >= *n_tiles) return;
  const int xb = wg - y * NXB;
  const int tm = tile_map[y];
  const int e = tm >> 16, m0 = tm & 0xFFFF;
  const int cnt = counts[e];
  const int off = offsets[e];
  const int n0 = xb * 128;

  __shared__ __align__(16) unsigned short As0[128 * 32], As1[128 * 32];
  __shared__ __align__(16) unsigned short Bs0[128 * 32], Bs1[128 * 32];

  const int tid = threadIdx.x;
  const int lane = tid & 63;
  const int wid = tid >> 6;
  const int rl = tid >> 2;                              // staging row 0..63
  const int srcc = ((tid & 3) ^ ((tid >> 3) & 3)) * 8;  // swizzled global slot
  const int d0 = tid * 8;                               // linear LDS dest (ushort idx)
  const int d1 = d0 + 64 * 32;

  const int r0 = m0 + rl, r1 = r0 + 64;
  const int s0 = (r0 < cnt) ? off + r0 : off;
  const int s1 = (r1 < cnt) ? off + r1 : off;
  const unsigned short* aptr0;
  const unsigned short* aptr1;
  if (MODE == EP_D) {
    aptr0 = A + (size_t)s0 * KD + srcc;
    aptr1 = A + (size_t)s1 * KD + srcc;
  } else {
    aptr0 = A + (size_t)tok_flat[s0] * KD + srcc;
    aptr1 = A + (size_t)tok_flat[s1] * KD + srcc;
  }
  const unsigned short* bptr0 = Bw + ((size_t)e * (NXB * 128) + n0 + rl) * KD + srcc;
  const unsigned short* bptr1 = bptr0 + (size_t)64 * KD;

  f32x4 zero = {0.f, 0.f, 0.f, 0.f};
  f32x4 acc[4][4];
#pragma unroll
  for (int i = 0; i < 4; ++i)
#pragma unroll
    for (int j = 0; j < 4; ++j) acc[i][j] = zero;

  const int wm = (wid >> 1) * 64;
  const int wn = (wid & 1) * 64;
  const int fr = lane & 15;
  const int cs = (((lane >> 4) ^ ((lane >> 1) & 3)) * 8);  // swizzled read slot

#define STAGE(AS, BS, kt)                 \
  {                                       \
    load_lds16(aptr0 + (kt), (AS) + d0);  \
    load_lds16(aptr1 + (kt), (AS) + d1);  \
    load_lds16(bptr0 + (kt), (BS) + d0);  \
    load_lds16(bptr1 + (kt), (BS) + d1);  \
  }

#define COMPUTE(AS, BS)                                                                \
  {                                                                                    \
    bf16x8 af[4], bf_[4];                                                              \
    _Pragma("unroll") for (int i = 0; i < 4; ++i) {                                    \
      af[i] = *reinterpret_cast<const bf16x8*>((AS) + (wm + i * 16 + fr) * 32 + cs);   \
      bf_[i] = *reinterpret_cast<const bf16x8*>((BS) + (wn + i * 16 + fr) * 32 + cs);  \
    }                                                                                  \
    _Pragma("unroll") for (int i = 0; i < 4; ++i)                                      \
      _Pragma("unroll") for (int j = 0; j < 4; ++j)                                    \
        acc[i][j] = __builtin_amdgcn_mfma_f32_16x16x32_bf16(af[i], bf_[j], acc[i][j], 0, 0, 0); \
  }

  STAGE(As0, Bs0, 0);
  __syncthreads();
#pragma unroll 1
  for (int kt = 0; kt < KD; kt += 64) {
    STAGE(As1, Bs1, kt + 32);
    COMPUTE(As0, Bs0);
    __syncthreads();
    if (kt + 64 < KD) STAGE(As0, Bs0, kt + 64);
    COMPUTE(As1, Bs1);
    __syncthreads();
  }
#undef STAGE
#undef COMPUTE

  const int lr = (lane >> 4) * 4;
  const int lc = lane & 15;
#pragma unroll
  for (int i = 0; i < 4; ++i) {
#pragma unroll
    for (int r = 0; r < 4; ++r) {
      int m = wm + i * 16 + lr + r;
      if (m0 + m < cnt) {
        int slot = off + m0 + m;
        if (MODE == EP_G) {
          size_t base = (size_t)slot * INTER + (size_t)(n0 + wn + lc);
#pragma unroll
          for (int j = 0; j < 4; ++j) Hf[base + j * 16] = f2bf(acc[i][j][r]);
        } else if (MODE == EP_U) {
          size_t base = (size_t)slot * INTER + (size_t)(n0 + wn + lc);
#pragma unroll
          for (int j = 0; j < 4; ++j) {
            float g = bf2f(Hf[base + j * 16]);
            float u = acc[i][j][r];
            float h = g / (1.f + __expf(-g)) * u;
            Hf[base + j * 16] = f2bf(h);
          }
        } else {
          int t = tok_flat[slot];
          float w = w_flat[slot];
          float* op = out + (size_t)t * HID + (size_t)(n0 + wn + lc);
#pragma unroll
          for (int j = 0; j < 4; ++j) atomicAdd(op + j * 16, w * acc[i][j][r]);
        }
      }
    }
  }
}

// ---------------- launch ----------------
extern "C" void kernel_launch(void* const* d_in, const int* in_sizes, int n_in,
                              void* d_out, int out_size, void* d_ws, size_t ws_size,
                              hipStream_t stream) {
  const float* x  = (const float*)d_in[0];
  const float* gw = (const float*)d_in[1];
  const float* wg = (const float*)d_in[2];
  const float* wu = (const float*)d_in[3];
  const float* wd = (const float*)d_in[4];
  float* out = (float*)d_out;
  char* ws = (char*)d_ws;

  // ws layout (bytes)
  int*   counts   = (int*)(ws + 0);          // 64
  int*   offsets  = (int*)(ws + 128);        // 64
  int*   n_tiles  = (int*)(ws + 192);        // 4
  int*   tile_map = (int*)(ws + 256);        // <=144*4
  int*   te       = (int*)(ws + 1024);       // 64 KiB
  float* tw       = (float*)(ws + 66560);    // 64 KiB
  int*   tok_flat = (int*)(ws + 132096);     // 64 KiB
  float* w_flat   = (float*)(ws + 197632);   // 64 KiB
  unsigned short* Xb  = (unsigned short*)(ws + 263168);     // 32 MiB
  unsigned short* Wgb = (unsigned short*)(ws + 33817600);   // 48 MiB
  unsigned short* Wub = (unsigned short*)(ws + 84149248);   // 48 MiB
  unsigned short* Wdb = (unsigned short*)(ws + 134480896);  // 48 MiB
  unsigned short* Hf  = (unsigned short*)(ws + 184812544);  // 24 MiB

  hipMemsetAsync(d_out, 0, (size_t)NTOK * HID * sizeof(float), stream);

  cvt_kernel<<<2048, 256, 0, stream>>>(wg, Wgb, NEXP * INTER * HID);
  cvt_kernel<<<2048, 256, 0, stream>>>(wu, Wub, NEXP * INTER * HID);
  cvt_kernel<<<2048, 256, 0, stream>>>(wd, Wdb, NEXP * HID * INTER);

  router_kernel<<<NTOK / 8, 256, 0, stream>>>(x, gw, te, tw, Xb);
  build_kernel<<<1, 256, 0, stream>>>(te, tw, counts, offsets, tok_flat, w_flat,
                                      tile_map, n_tiles);

  gemm_kernel<EP_G, 6, HID><<<144 * 6, 256, 0, stream>>>(
      Xb, Wgb, counts, offsets, tok_flat, w_flat, tile_map, n_tiles, Hf, out);
  gemm_kernel<EP_U, 6, HID><<<144 * 6, 256, 0, stream>>>(
      Xb, Wub, counts, offsets, tok_flat, w_flat, tile_map, n_tiles, Hf, out);
  gemm_kernel<EP_D, 16, INTER><<<144 * 16, 256, 0, stream>>>(
      Hf, Wdb, counts, offsets, tok_flat, w_flat, tile_map, n_tiles, Hf, out);
}

// Round 5
// 484.783 us; speedup vs baseline: 1.8089x; 1.0649x over previous
//
#include <hip/hip_runtime.h>
#include <hip/hip_bf16.h>

#define NTOK 8192
#define HID 2048
#define INTER 768
#define NEXP 16

typedef __bf16 bf16x8 __attribute__((ext_vector_type(8)));
typedef float f32x4 __attribute__((ext_vector_type(4)));

typedef const __attribute__((address_space(1))) void gvoid_t;
typedef __attribute__((address_space(3))) void lvoid_t;

static __device__ __forceinline__ void load_lds16(const void* g, void* l) {
  __builtin_amdgcn_global_load_lds((gvoid_t*)g, (lvoid_t*)l, 16, 0, 0);
}

static __device__ __forceinline__ unsigned short f2bf(float f) {
  unsigned int u = __float_as_uint(f);
  u += 0x7FFFu + ((u >> 16) & 1u);
  return (unsigned short)(u >> 16);
}

static __device__ __forceinline__ float bf2f(unsigned short b) {
  return __uint_as_float(((unsigned int)b) << 16);
}

// ---------------- fp32 -> bf16 conversion (weights) ----------------
__global__ __launch_bounds__(256) void cvt_kernel(const float* __restrict__ src,
                                                  unsigned short* __restrict__ dst, int n) {
  int i = (blockIdx.x * 256 + threadIdx.x) * 4;
  int stride = gridDim.x * 256 * 4;
  for (; i < n; i += stride) {
    float4 v = *reinterpret_cast<const float4*>(src + i);
    ushort4 o;
    o.x = f2bf(v.x); o.y = f2bf(v.y); o.z = f2bf(v.z); o.w = f2bf(v.w);
    *reinterpret_cast<ushort4*>(dst + i) = o;
  }
}

// ---------------- router: barrier-free, LDS-free, atomic-free ----------------
__global__ __launch_bounds__(256) void router_kernel(const float* __restrict__ x,
                                                     const float* __restrict__ gw,
                                                     int* __restrict__ te,
                                                     float* __restrict__ tw,
                                                     unsigned short* __restrict__ Xb) {
  const int lane = threadIdx.x & 63;
  const int wid = threadIdx.x >> 6;
  const int t0 = (blockIdx.x * 4 + wid) * 2;  // this wave's two tokens
  const float4* xa = reinterpret_cast<const float4*>(x + (size_t)t0 * HID);
  const float4* xb = xa + HID / 4;
  const float4* g4 = reinterpret_cast<const float4*>(gw);

  float4 va[8], vb[8];
#pragma unroll
  for (int j = 0; j < 8; ++j) {
    va[j] = xa[lane + 64 * j];
    vb[j] = xb[lane + 64 * j];
  }
  ushort4* oa = reinterpret_cast<ushort4*>(Xb + (size_t)t0 * HID);
  ushort4* ob = oa + HID / 4;
#pragma unroll
  for (int j = 0; j < 8; ++j) {
    ushort4 u;
    u.x = f2bf(va[j].x); u.y = f2bf(va[j].y); u.z = f2bf(va[j].z); u.w = f2bf(va[j].w);
    oa[lane + 64 * j] = u;
    u.x = f2bf(vb[j].x); u.y = f2bf(vb[j].y); u.z = f2bf(vb[j].z); u.w = f2bf(vb[j].w);
    ob[lane + 64 * j] = u;
  }

  float accA[NEXP], accB[NEXP];
#pragma unroll
  for (int e = 0; e < NEXP; ++e) { accA[e] = 0.f; accB[e] = 0.f; }
#pragma unroll
  for (int e = 0; e < NEXP; ++e) {
#pragma unroll
    for (int j = 0; j < 8; ++j) {
      float4 g = g4[e * (HID / 4) + lane + 64 * j];
      accA[e] += va[j].x * g.x + va[j].y * g.y + va[j].z * g.z + va[j].w * g.w;
      accB[e] += vb[j].x * g.x + vb[j].y * g.y + vb[j].z * g.z + vb[j].w * g.w;
    }
  }
#pragma unroll
  for (int e = 0; e < NEXP; ++e) {
#pragma unroll
    for (int m = 32; m >= 1; m >>= 1) {
      accA[e] += __shfl_xor(accA[e], m);
      accB[e] += __shfl_xor(accB[e], m);
    }
  }
  if (lane == 0) {
#pragma unroll
    for (int k = 0; k < 2; ++k) {
      const float* acc = k ? accB : accA;
      int t = t0 + k;
      float b0 = -1e30f; int i0 = 0;
#pragma unroll
      for (int e = 0; e < NEXP; ++e) { if (acc[e] > b0) { b0 = acc[e]; i0 = e; } }
      float b1 = -1e30f; int i1 = 0;
#pragma unroll
      for (int e = 0; e < NEXP; ++e) { if (e != i0 && acc[e] > b1) { b1 = acc[e]; i1 = e; } }
      float w0 = 1.f / (1.f + __expf(b1 - b0));
      te[2 * t] = i0; te[2 * t + 1] = i1;
      tw[2 * t] = w0; tw[2 * t + 1] = 1.f - w0;
    }
  }
}

// ---------------- build: histogram + scan + scatter, ONE block, NO atomics ----------------
__global__ __launch_bounds__(256) void build_kernel(
    const int* __restrict__ te, const float* __restrict__ tw,
    int* __restrict__ counts, int* __restrict__ offsets,
    int* __restrict__ tok_flat, float* __restrict__ w_flat,
    int* __restrict__ tok_slot,
    int* __restrict__ tile_map, int* __restrict__ n_tiles) {
  __shared__ int lds_cnt[NEXP][257];
  __shared__ int lds_off[NEXP];
  const int tid = threadIdx.x;
  const int lane = tid & 63;
  const int wv = tid >> 6;

  int cnt[NEXP];
#pragma unroll
  for (int ex = 0; ex < NEXP; ++ex) cnt[ex] = 0;
  for (int i = 0; i < 64; ++i) {
    int e = te[tid * 64 + i];
#pragma unroll
    for (int ex = 0; ex < NEXP; ++ex) cnt[ex] += (e == ex) ? 1 : 0;
  }
#pragma unroll
  for (int ex = 0; ex < NEXP; ++ex) lds_cnt[ex][tid] = cnt[ex];
  __syncthreads();

  for (int ex = wv * 4; ex < wv * 4 + 4; ++ex) {
    int carry = 0;
    for (int c = 0; c < 4; ++c) {
      int v = lds_cnt[ex][c * 64 + lane];
      int s = v;
#pragma unroll
      for (int d = 1; d < 64; d <<= 1) {
        int o = __shfl_up(s, d);
        if (lane >= d) s += o;
      }
      lds_cnt[ex][c * 64 + lane] = carry + s - v;  // exclusive
      carry += __shfl(s, 63);
    }
    if (lane == 0) lds_cnt[ex][256] = carry;
  }
  __syncthreads();

  if (tid == 0) {
    int run = 0, nt = 0;
    for (int e = 0; e < NEXP; ++e) {
      int tot = lds_cnt[e][256];
      counts[e] = tot;
      offsets[e] = run;
      lds_off[e] = run;
      for (int m0 = 0; m0 < tot; m0 += 128) tile_map[nt++] = (e << 16) | m0;
      run += tot;
    }
    *n_tiles = nt;
  }
  __syncthreads();

  int base[NEXP];
#pragma unroll
  for (int ex = 0; ex < NEXP; ++ex) base[ex] = lds_off[ex] + lds_cnt[ex][tid];
  for (int i = 0; i < 64; ++i) {
    int idx = tid * 64 + i;
    int e = te[idx];
    float w = tw[idx];
    int pos = 0;
#pragma unroll
    for (int ex = 0; ex < NEXP; ++ex) {
      if (e == ex) { pos = base[ex]; base[ex] = pos + 1; }
    }
    tok_flat[pos] = idx >> 1;
    w_flat[pos] = w;
    tok_slot[idx] = pos;  // inverse map for combine
  }
}

// Epilogue modes
#define EP_G 0  // write raw gate-proj (bf16) to Hf
#define EP_U 1  // read g from Hf, write silu(g)*u to Hf
#define EP_Y 2  // write w * y (bf16) to slot-major Yf (no atomics)

// Unified GEMM: BM=128, BN=128, 4 waves 2x2. Barrier-pair per BK=64 (32 MFMA),
// m97-style. LDS slot-XOR swizzle (linear LDS dest, permuted GLOBAL source
// slot, same XOR on ds_read) -> zero bank conflicts (verified r2-r4).
// XCD-chunk blockIdx swizzle (grid % 8 == 0).
template <int MODE, int NXB, int KD>
__global__ __launch_bounds__(256, 3) void gemm_kernel(
    const unsigned short* __restrict__ A,    // Xb (G/U) or Hf (Y)
    const unsigned short* __restrict__ Bw,   // weights [E][NXB*128][KD] bf16
    const int* __restrict__ counts, const int* __restrict__ offsets,
    const int* __restrict__ tok_flat, const float* __restrict__ w_flat,
    const int* __restrict__ tile_map, const int* __restrict__ n_tiles,
    unsigned short* __restrict__ Hf, float* __restrict__ out) {
  const int bid = blockIdx.x;
  const int cpx = gridDim.x >> 3;
  const int wg = (bid & 7) * cpx + (bid >> 3);
  const int y = wg / NXB;
  if (y >= *n_tiles) return;
  const int xb = wg - y * NXB;
  const int tm = tile_map[y];
  const int e = tm >> 16, m0 = tm & 0xFFFF;
  const int cnt = counts[e];
  const int off = offsets[e];
  const int n0 = xb * 128;

  __shared__ __align__(16) unsigned short As0[128 * 32], As1[128 * 32];
  __shared__ __align__(16) unsigned short Bs0[128 * 32], Bs1[128 * 32];

  const int tid = threadIdx.x;
  const int lane = tid & 63;
  const int wid = tid >> 6;
  const int rl = tid >> 2;                              // staging row 0..63
  const int srcc = ((tid & 3) ^ ((tid >> 3) & 3)) * 8;  // swizzled global slot
  const int d0 = tid * 8;                               // linear LDS dest (ushort idx)
  const int d1 = d0 + 64 * 32;

  const int r0 = m0 + rl, r1 = r0 + 64;
  const int s0 = (r0 < cnt) ? off + r0 : off;
  const int s1 = (r1 < cnt) ? off + r1 : off;
  const unsigned short* aptr0;
  const unsigned short* aptr1;
  if (MODE == EP_Y) {
    aptr0 = A + (size_t)s0 * KD + srcc;
    aptr1 = A + (size_t)s1 * KD + srcc;
  } else {
    aptr0 = A + (size_t)tok_flat[s0] * KD + srcc;
    aptr1 = A + (size_t)tok_flat[s1] * KD + srcc;
  }
  const unsigned short* bptr0 = Bw + ((size_t)e * (NXB * 128) + n0 + rl) * KD + srcc;
  const unsigned short* bptr1 = bptr0 + (size_t)64 * KD;

  f32x4 zero = {0.f, 0.f, 0.f, 0.f};
  f32x4 acc[4][4];
#pragma unroll
  for (int i = 0; i < 4; ++i)
#pragma unroll
    for (int j = 0; j < 4; ++j) acc[i][j] = zero;

  const int wm = (wid >> 1) * 64;
  const int wn = (wid & 1) * 64;
  const int fr = lane & 15;
  const int cs = (((lane >> 4) ^ ((lane >> 1) & 3)) * 8);  // swizzled read slot

#define STAGE(AS, BS, kt)                 \
  {                                       \
    load_lds16(aptr0 + (kt), (AS) + d0);  \
    load_lds16(aptr1 + (kt), (AS) + d1);  \
    load_lds16(bptr0 + (kt), (BS) + d0);  \
    load_lds16(bptr1 + (kt), (BS) + d1);  \
  }

#define COMPUTE(AS, BS)                                                                \
  {                                                                                    \
    bf16x8 af[4], bf_[4];                                                              \
    _Pragma("unroll") for (int i = 0; i < 4; ++i) {                                    \
      af[i] = *reinterpret_cast<const bf16x8*>((AS) + (wm + i * 16 + fr) * 32 + cs);   \
      bf_[i] = *reinterpret_cast<const bf16x8*>((BS) + (wn + i * 16 + fr) * 32 + cs);  \
    }                                                                                  \
    _Pragma("unroll") for (int i = 0; i < 4; ++i)                                      \
      _Pragma("unroll") for (int j = 0; j < 4; ++j)                                    \
        acc[i][j] = __builtin_amdgcn_mfma_f32_16x16x32_bf16(af[i], bf_[j], acc[i][j], 0, 0, 0); \
  }

  // m97-style: one barrier-pair per BK=64 (32 MFMA/pair); cross-block TLP
  // hides the stage drain (3-4 blocks/CU).
#pragma unroll 1
  for (int kt = 0; kt < KD; kt += 64) {
    STAGE(As0, Bs0, kt);
    STAGE(As1, Bs1, kt + 32);
    __syncthreads();
    COMPUTE(As0, Bs0);
    COMPUTE(As1, Bs1);
    __syncthreads();
  }
#undef STAGE
#undef COMPUTE

  const int lr = (lane >> 4) * 4;
  const int lc = lane & 15;
#pragma unroll
  for (int i = 0; i < 4; ++i) {
#pragma unroll
    for (int r = 0; r < 4; ++r) {
      int m = wm + i * 16 + lr + r;
      if (m0 + m < cnt) {
        int slot = off + m0 + m;
        if (MODE == EP_G) {
          size_t base = (size_t)slot * INTER + (size_t)(n0 + wn + lc);
#pragma unroll
          for (int j = 0; j < 4; ++j) Hf[base + j * 16] = f2bf(acc[i][j][r]);
        } else if (MODE == EP_U) {
          size_t base = (size_t)slot * INTER + (size_t)(n0 + wn + lc);
#pragma unroll
          for (int j = 0; j < 4; ++j) {
            float g = bf2f(Hf[base + j * 16]);
            float u = acc[i][j][r];
            float h = g / (1.f + __expf(-g)) * u;
            Hf[base + j * 16] = f2bf(h);
          }
        } else {  // EP_Y: plain bf16 stores of w*y into slot-major Yf (= Hf arg)
          float w = w_flat[slot];
          size_t base = (size_t)slot * HID + (size_t)(n0 + wn + lc);
#pragma unroll
          for (int j = 0; j < 4; ++j) Hf[base + j * 16] = f2bf(w * acc[i][j][r]);
        }
      }
    }
  }
}

// ---------------- combine: out[t] = Yf[slot0] + Yf[slot1] ----------------
__global__ __launch_bounds__(256) void combine_kernel(const unsigned short* __restrict__ Yf,
                                                      const int* __restrict__ tok_slot,
                                                      float* __restrict__ out) {
  const int t = blockIdx.x;
  const int c = threadIdx.x * 8;
  const int s0 = tok_slot[2 * t];
  const int s1 = tok_slot[2 * t + 1];
  const ushort4* p0 = reinterpret_cast<const ushort4*>(Yf + (size_t)s0 * HID + c);
  const ushort4* p1 = reinterpret_cast<const ushort4*>(Yf + (size_t)s1 * HID + c);
  ushort4 a0 = p0[0], a1 = p0[1];
  ushort4 b0 = p1[0], b1 = p1[1];
  float4 o0, o1;
  o0.x = bf2f(a0.x) + bf2f(b0.x);
  o0.y = bf2f(a0.y) + bf2f(b0.y);
  o0.z = bf2f(a0.z) + bf2f(b0.z);
  o0.w = bf2f(a0.w) + bf2f(b0.w);
  o1.x = bf2f(a1.x) + bf2f(b1.x);
  o1.y = bf2f(a1.y) + bf2f(b1.y);
  o1.z = bf2f(a1.z) + bf2f(b1.z);
  o1.w = bf2f(a1.w) + bf2f(b1.w);
  float4* op = reinterpret_cast<float4*>(out + (size_t)t * HID + c);
  op[0] = o0;
  op[1] = o1;
}

// ---------------- launch ----------------
extern "C" void kernel_launch(void* const* d_in, const int* in_sizes, int n_in,
                              void* d_out, int out_size, void* d_ws, size_t ws_size,
                              hipStream_t stream) {
  const float* x  = (const float*)d_in[0];
  const float* gw = (const float*)d_in[1];
  const float* wg = (const float*)d_in[2];
  const float* wu = (const float*)d_in[3];
  const float* wd = (const float*)d_in[4];
  float* out = (float*)d_out;
  char* ws = (char*)d_ws;

  // ws layout (bytes)
  int*   counts   = (int*)(ws + 0);          // 64
  int*   offsets  = (int*)(ws + 128);        // 64
  int*   n_tiles  = (int*)(ws + 192);        // 4
  int*   tile_map = (int*)(ws + 256);        // <=144*4
  int*   te       = (int*)(ws + 1024);       // 64 KiB
  float* tw       = (float*)(ws + 66560);    // 64 KiB
  int*   tok_flat = (int*)(ws + 132096);     // 64 KiB
  float* w_flat   = (float*)(ws + 197632);   // 64 KiB
  unsigned short* Xb  = (unsigned short*)(ws + 263168);     // 32 MiB
  unsigned short* Wgb = (unsigned short*)(ws + 33817600);   // 48 MiB
  unsigned short* Wub = (unsigned short*)(ws + 84149248);   // 48 MiB
  unsigned short* Wdb = (unsigned short*)(ws + 134480896);  // 48 MiB
  unsigned short* Hf  = (unsigned short*)(ws + 184812544);  // 24 MiB
  int*   tok_slot = (int*)(ws + 209978368);  // 64 KiB
  // Yf [16384][2048] bf16 = 64 MiB, aliases Wgb+Wub (dead after EP_U)
  unsigned short* Yf  = Wgb;

  cvt_kernel<<<2048, 256, 0, stream>>>(wg, Wgb, NEXP * INTER * HID);
  cvt_kernel<<<2048, 256, 0, stream>>>(wu, Wub, NEXP * INTER * HID);
  cvt_kernel<<<2048, 256, 0, stream>>>(wd, Wdb, NEXP * HID * INTER);

  router_kernel<<<NTOK / 8, 256, 0, stream>>>(x, gw, te, tw, Xb);
  build_kernel<<<1, 256, 0, stream>>>(te, tw, counts, offsets, tok_flat, w_flat,
                                      tok_slot, tile_map, n_tiles);

  gemm_kernel<EP_G, 6, HID><<<144 * 6, 256, 0, stream>>>(
      Xb, Wgb, counts, offsets, tok_flat, w_flat, tile_map, n_tiles, Hf, out);
  gemm_kernel<EP_U, 6, HID><<<144 * 6, 256, 0, stream>>>(
      Xb, Wub, counts, offsets, tok_flat, w_flat, tile_map, n_tiles, Hf, out);
  gemm_kernel<EP_Y, 16, INTER><<<144 * 16, 256, 0, stream>>>(
      Hf, Wdb, counts, offsets, tok_flat, w_flat, tile_map, n_tiles, Yf, out);
  combine_kernel<<<NTOK, 256, 0, stream>>>(Yf, tok_slot, out);
}

// Round 7
// 449.786 us; speedup vs baseline: 1.9497x; 1.0778x over previous
//
#include <hip/hip_runtime.h>
#include <hip/hip_bf16.h>

#define NTOK 8192
#define HID 2048
#define INTER 768
#define NEXP 16

typedef __bf16 bf16x8 __attribute__((ext_vector_type(8)));
typedef float f32x4 __attribute__((ext_vector_type(4)));

typedef const __attribute__((address_space(1))) void gvoid_t;
typedef __attribute__((address_space(3))) void lvoid_t;

static __device__ __forceinline__ void load_lds16(const void* g, void* l) {
  __builtin_amdgcn_global_load_lds((gvoid_t*)g, (lvoid_t*)l, 16, 0, 0);
}

static __device__ __forceinline__ unsigned short f2bf(float f) {
  unsigned int u = __float_as_uint(f);
  u += 0x7FFFu + ((u >> 16) & 1u);
  return (unsigned short)(u >> 16);
}

static __device__ __forceinline__ float bf2f(unsigned short b) {
  return __uint_as_float(((unsigned int)b) << 16);
}

// ---------------- fp32 -> bf16 conversion (weights) ----------------
__global__ __launch_bounds__(256) void cvt_kernel(const float* __restrict__ src,
                                                  unsigned short* __restrict__ dst, int n) {
  int i = (blockIdx.x * 256 + threadIdx.x) * 4;
  int stride = gridDim.x * 256 * 4;
  for (; i < n; i += stride) {
    float4 v = *reinterpret_cast<const float4*>(src + i);
    ushort4 o;
    o.x = f2bf(v.x); o.y = f2bf(v.y); o.z = f2bf(v.z); o.w = f2bf(v.w);
    *reinterpret_cast<ushort4*>(dst + i) = o;
  }
}

// ---------------- router: barrier-free, LDS-free, atomic-free ----------------
__global__ __launch_bounds__(256) void router_kernel(const float* __restrict__ x,
                                                     const float* __restrict__ gw,
                                                     int* __restrict__ te,
                                                     float* __restrict__ tw,
                                                     unsigned short* __restrict__ Xb) {
  const int lane = threadIdx.x & 63;
  const int wid = threadIdx.x >> 6;
  const int t0 = (blockIdx.x * 4 + wid) * 2;  // this wave's two tokens
  const float4* xa = reinterpret_cast<const float4*>(x + (size_t)t0 * HID);
  const float4* xb = xa + HID / 4;
  const float4* g4 = reinterpret_cast<const float4*>(gw);

  float4 va[8], vb[8];
#pragma unroll
  for (int j = 0; j < 8; ++j) {
    va[j] = xa[lane + 64 * j];
    vb[j] = xb[lane + 64 * j];
  }
  ushort4* oa = reinterpret_cast<ushort4*>(Xb + (size_t)t0 * HID);
  ushort4* ob = oa + HID / 4;
#pragma unroll
  for (int j = 0; j < 8; ++j) {
    ushort4 u;
    u.x = f2bf(va[j].x); u.y = f2bf(va[j].y); u.z = f2bf(va[j].z); u.w = f2bf(va[j].w);
    oa[lane + 64 * j] = u;
    u.x = f2bf(vb[j].x); u.y = f2bf(vb[j].y); u.z = f2bf(vb[j].z); u.w = f2bf(vb[j].w);
    ob[lane + 64 * j] = u;
  }

  float accA[NEXP], accB[NEXP];
#pragma unroll
  for (int e = 0; e < NEXP; ++e) { accA[e] = 0.f; accB[e] = 0.f; }
#pragma unroll
  for (int e = 0; e < NEXP; ++e) {
#pragma unroll
    for (int j = 0; j < 8; ++j) {
      float4 g = g4[e * (HID / 4) + lane + 64 * j];
      accA[e] += va[j].x * g.x + va[j].y * g.y + va[j].z * g.z + va[j].w * g.w;
      accB[e] += vb[j].x * g.x + vb[j].y * g.y + vb[j].z * g.z + vb[j].w * g.w;
    }
  }
#pragma unroll
  for (int e = 0; e < NEXP; ++e) {
#pragma unroll
    for (int m = 32; m >= 1; m >>= 1) {
      accA[e] += __shfl_xor(accA[e], m);
      accB[e] += __shfl_xor(accB[e], m);
    }
  }
  if (lane == 0) {
#pragma unroll
    for (int k = 0; k < 2; ++k) {
      const float* acc = k ? accB : accA;
      int t = t0 + k;
      float b0 = -1e30f; int i0 = 0;
#pragma unroll
      for (int e = 0; e < NEXP; ++e) { if (acc[e] > b0) { b0 = acc[e]; i0 = e; } }
      float b1 = -1e30f; int i1 = 0;
#pragma unroll
      for (int e = 0; e < NEXP; ++e) { if (e != i0 && acc[e] > b1) { b1 = acc[e]; i1 = e; } }
      float w0 = 1.f / (1.f + __expf(b1 - b0));
      te[2 * t] = i0; te[2 * t + 1] = i1;
      tw[2 * t] = w0; tw[2 * t + 1] = 1.f - w0;
    }
  }
}

// ---------------- build: histogram + scan + scatter, ONE block, NO atomics ----------------
__global__ __launch_bounds__(256) void build_kernel(
    const int* __restrict__ te, const float* __restrict__ tw,
    int* __restrict__ counts, int* __restrict__ offsets,
    int* __restrict__ tok_flat, float* __restrict__ w_flat,
    int* __restrict__ tok_slot,
    int* __restrict__ tile_map, int* __restrict__ n_tiles) {
  __shared__ int lds_cnt[NEXP][257];
  __shared__ int lds_off[NEXP];
  const int tid = threadIdx.x;
  const int lane = tid & 63;
  const int wv = tid >> 6;

  int cnt[NEXP];
#pragma unroll
  for (int ex = 0; ex < NEXP; ++ex) cnt[ex] = 0;
  for (int i = 0; i < 64; ++i) {
    int e = te[tid * 64 + i];
#pragma unroll
    for (int ex = 0; ex < NEXP; ++ex) cnt[ex] += (e == ex) ? 1 : 0;
  }
#pragma unroll
  for (int ex = 0; ex < NEXP; ++ex) lds_cnt[ex][tid] = cnt[ex];
  __syncthreads();

  for (int ex = wv * 4; ex < wv * 4 + 4; ++ex) {
    int carry = 0;
    for (int c = 0; c < 4; ++c) {
      int v = lds_cnt[ex][c * 64 + lane];
      int s = v;
#pragma unroll
      for (int d = 1; d < 64; d <<= 1) {
        int o = __shfl_up(s, d);
        if (lane >= d) s += o;
      }
      lds_cnt[ex][c * 64 + lane] = carry + s - v;  // exclusive
      carry += __shfl(s, 63);
    }
    if (lane == 0) lds_cnt[ex][256] = carry;
  }
  __syncthreads();

  if (tid == 0) {
    int run = 0, nt = 0;
    for (int e = 0; e < NEXP; ++e) {
      int tot = lds_cnt[e][256];
      counts[e] = tot;
      offsets[e] = run;
      lds_off[e] = run;
      for (int m0 = 0; m0 < tot; m0 += 128) tile_map[nt++] = (e << 16) | m0;
      run += tot;
    }
    *n_tiles = nt;
  }
  __syncthreads();

  int base[NEXP];
#pragma unroll
  for (int ex = 0; ex < NEXP; ++ex) base[ex] = lds_off[ex] + lds_cnt[ex][tid];
  for (int i = 0; i < 64; ++i) {
    int idx = tid * 64 + i;
    int e = te[idx];
    float w = tw[idx];
    int pos = 0;
#pragma unroll
    for (int ex = 0; ex < NEXP; ++ex) {
      if (e == ex) { pos = base[ex]; base[ex] = pos + 1; }
    }
    tok_flat[pos] = idx >> 1;
    w_flat[pos] = w;
    tok_slot[idx] = pos;  // inverse map for combine
  }
}

// ---------------- fused gate+up GEMM: Hf = silu(X Wg^T) * (X Wu^T) ----------------
// All staging via global_load_lds from pre-converted bf16 (r2/r3-proven fused
// structure + r5-proven barrier/BK=64 schedule). LDS slot-XOR swizzle: linear
// LDS dest, permuted GLOBAL source slot, same XOR on ds_read (zero conflicts,
// verified r2-r5). XCD-chunk blockIdx swizzle (grid % 8 == 0).
__global__ __launch_bounds__(256, 2) void gemm_gu_kernel(
    const unsigned short* __restrict__ Xb,   // [NTOK][HID] bf16
    const unsigned short* __restrict__ Wg,   // [E][INTER][HID] bf16
    const unsigned short* __restrict__ Wu,   // [E][INTER][HID] bf16
    const int* __restrict__ counts, const int* __restrict__ offsets,
    const int* __restrict__ tok_flat,
    const int* __restrict__ tile_map, const int* __restrict__ n_tiles,
    unsigned short* __restrict__ Hf) {       // [2*NTOK][INTER] bf16
  const int bid = blockIdx.x;
  const int cpx = gridDim.x >> 3;            // 864/8 = 108
  const int wg = (bid & 7) * cpx + (bid >> 3);
  const int y = wg / 6;
  if (y >= *n_tiles) return;
  const int xb = wg - y * 6;
  const int tm = tile_map[y];
  const int e = tm >> 16, m0 = tm & 0xFFFF;
  const int cnt = counts[e];
  const int off = offsets[e];
  const int n0 = xb * 128;

  __shared__ __align__(16) unsigned short As0[128 * 32], As1[128 * 32];
  __shared__ __align__(16) unsigned short Bg0[128 * 32], Bg1[128 * 32];
  __shared__ __align__(16) unsigned short Bu0[128 * 32], Bu1[128 * 32];

  const int tid = threadIdx.x;
  const int lane = tid & 63;
  const int wid = tid >> 6;
  const int rl = tid >> 2;                              // staging row 0..63
  const int srcc = ((tid & 3) ^ ((tid >> 3) & 3)) * 8;  // swizzled global slot
  const int d0 = tid * 8;                               // linear LDS dest (ushort idx)
  const int d1 = d0 + 64 * 32;

  const int r0 = m0 + rl, r1 = r0 + 64;
  const int s0 = (r0 < cnt) ? off + r0 : off;
  const int s1 = (r1 < cnt) ? off + r1 : off;
  const unsigned short* aptr0 = Xb + (size_t)tok_flat[s0] * HID + srcc;
  const unsigned short* aptr1 = Xb + (size_t)tok_flat[s1] * HID + srcc;
  const unsigned short* gptr0 = Wg + ((size_t)e * INTER + n0 + rl) * HID + srcc;
  const unsigned short* gptr1 = gptr0 + (size_t)64 * HID;
  const unsigned short* uptr0 = Wu + ((size_t)e * INTER + n0 + rl) * HID + srcc;
  const unsigned short* uptr1 = uptr0 + (size_t)64 * HID;

  f32x4 zero = {0.f, 0.f, 0.f, 0.f};
  f32x4 accG[4][4], accU[4][4];
#pragma unroll
  for (int i = 0; i < 4; ++i)
#pragma unroll
    for (int j = 0; j < 4; ++j) { accG[i][j] = zero; accU[i][j] = zero; }

  const int wm = (wid >> 1) * 64;
  const int wn = (wid & 1) * 64;
  const int fr = lane & 15;
  const int cs = (((lane >> 4) ^ ((lane >> 1) & 3)) * 8);  // swizzled read slot

#define STAGE_GU(AS, BGS, BUS, kt)           \
  {                                          \
    load_lds16(aptr0 + (kt), (AS) + d0);     \
    load_lds16(aptr1 + (kt), (AS) + d1);     \
    load_lds16(gptr0 + (kt), (BGS) + d0);    \
    load_lds16(gptr1 + (kt), (BGS) + d1);    \
    load_lds16(uptr0 + (kt), (BUS) + d0);    \
    load_lds16(uptr1 + (kt), (BUS) + d1);    \
  }

#define COMPUTE_GU(AS, BGS, BUS)                                                       \
  {                                                                                    \
    bf16x8 af[4], bg[4], bu[4];                                                        \
    _Pragma("unroll") for (int i = 0; i < 4; ++i) {                                    \
      af[i] = *reinterpret_cast<const bf16x8*>((AS) + (wm + i * 16 + fr) * 32 + cs);   \
      bg[i] = *reinterpret_cast<const bf16x8*>((BGS) + (wn + i * 16 + fr) * 32 + cs);  \
      bu[i] = *reinterpret_cast<const bf16x8*>((BUS) + (wn + i * 16 + fr) * 32 + cs);  \
    }                                                                                  \
    _Pragma("unroll") for (int i = 0; i < 4; ++i)                                      \
      _Pragma("unroll") for (int j = 0; j < 4; ++j) {                                  \
        accG[i][j] = __builtin_amdgcn_mfma_f32_16x16x32_bf16(af[i], bg[j], accG[i][j], 0, 0, 0); \
        accU[i][j] = __builtin_amdgcn_mfma_f32_16x16x32_bf16(af[i], bu[j], accU[i][j], 0, 0, 0); \
      }                                                                                \
  }

#pragma unroll 1
  for (int kt = 0; kt < HID; kt += 64) {
    STAGE_GU(As0, Bg0, Bu0, kt);
    STAGE_GU(As1, Bg1, Bu1, kt + 32);
    __syncthreads();
    COMPUTE_GU(As0, Bg0, Bu0);
    COMPUTE_GU(As1, Bg1, Bu1);
    __syncthreads();
  }
#undef STAGE_GU
#undef COMPUTE_GU

  // epilogue: h = silu(g) * u (fp32 g), bf16 store. D frag: row=(lane>>4)*4+reg, col=lane&15
  const int lr = (lane >> 4) * 4;
  const int lc = lane & 15;
#pragma unroll
  for (int i = 0; i < 4; ++i) {
#pragma unroll
    for (int r = 0; r < 4; ++r) {
      int m = wm + i * 16 + lr + r;
      if (m0 + m < cnt) {
        size_t base = (size_t)(off + m0 + m) * INTER + (size_t)(n0 + wn + lc);
#pragma unroll
        for (int j = 0; j < 4; ++j) {
          float g = accG[i][j][r];
          float u = accU[i][j][r];
          float h = g / (1.f + __expf(-g)) * u;
          Hf[base + j * 16] = f2bf(h);
        }
      }
    }
  }
}

// ---------------- down-proj GEMM (byte-identical to r5 EP_Y path) ----------------
__global__ __launch_bounds__(256, 3) void gemm_y_kernel(
    const unsigned short* __restrict__ Hf,   // [2*NTOK][INTER] bf16
    const unsigned short* __restrict__ Wd,   // [E][HID][INTER] bf16
    const int* __restrict__ counts, const int* __restrict__ offsets,
    const float* __restrict__ w_flat,
    const int* __restrict__ tile_map, const int* __restrict__ n_tiles,
    unsigned short* __restrict__ Yf) {       // [2*NTOK][HID] bf16
  const int bid = blockIdx.x;
  const int cpx = gridDim.x >> 3;            // 2304/8 = 288
  const int wg = (bid & 7) * cpx + (bid >> 3);
  const int y = wg / 16;
  if (y >= *n_tiles) return;
  const int xb = wg - y * 16;
  const int tm = tile_map[y];
  const int e = tm >> 16, m0 = tm & 0xFFFF;
  const int cnt = counts[e];
  const int off = offsets[e];
  const int n0 = xb * 128;

  __shared__ __align__(16) unsigned short As0[128 * 32], As1[128 * 32];
  __shared__ __align__(16) unsigned short Bs0[128 * 32], Bs1[128 * 32];

  const int tid = threadIdx.x;
  const int lane = tid & 63;
  const int wid = tid >> 6;
  const int rl = tid >> 2;
  const int srcc = ((tid & 3) ^ ((tid >> 3) & 3)) * 8;
  const int d0 = tid * 8;
  const int d1 = d0 + 64 * 32;

  const int r0 = m0 + rl, r1 = r0 + 64;
  const int s0 = (r0 < cnt) ? off + r0 : off;
  const int s1 = (r1 < cnt) ? off + r1 : off;
  const unsigned short* aptr0 = Hf + (size_t)s0 * INTER + srcc;
  const unsigned short* aptr1 = Hf + (size_t)s1 * INTER + srcc;
  const unsigned short* bptr0 = Wd + ((size_t)e * HID + n0 + rl) * INTER + srcc;
  const unsigned short* bptr1 = bptr0 + (size_t)64 * INTER;

  f32x4 zero = {0.f, 0.f, 0.f, 0.f};
  f32x4 acc[4][4];
#pragma unroll
  for (int i = 0; i < 4; ++i)
#pragma unroll
    for (int j = 0; j < 4; ++j) acc[i][j] = zero;

  const int wm = (wid >> 1) * 64;
  const int wn = (wid & 1) * 64;
  const int fr = lane & 15;
  const int cs = (((lane >> 4) ^ ((lane >> 1) & 3)) * 8);

#define STAGE_Y(AS, BS, kt)               \
  {                                       \
    load_lds16(aptr0 + (kt), (AS) + d0);  \
    load_lds16(aptr1 + (kt), (AS) + d1);  \
    load_lds16(bptr0 + (kt), (BS) + d0);  \
    load_lds16(bptr1 + (kt), (BS) + d1);  \
  }

#define COMPUTE_Y(AS, BS)                                                              \
  {                                                                                    \
    bf16x8 af[4], bf_[4];                                                              \
    _Pragma("unroll") for (int i = 0; i < 4; ++i) {                                    \
      af[i] = *reinterpret_cast<const bf16x8*>((AS) + (wm + i * 16 + fr) * 32 + cs);   \
      bf_[i] = *reinterpret_cast<const bf16x8*>((BS) + (wn + i * 16 + fr) * 32 + cs);  \
    }                                                                                  \
    _Pragma("unroll") for (int i = 0; i < 4; ++i)                                      \
      _Pragma("unroll") for (int j = 0; j < 4; ++j)                                    \
        acc[i][j] = __builtin_amdgcn_mfma_f32_16x16x32_bf16(af[i], bf_[j], acc[i][j], 0, 0, 0); \
  }

#pragma unroll 1
  for (int kt = 0; kt < INTER; kt += 64) {
    STAGE_Y(As0, Bs0, kt);
    STAGE_Y(As1, Bs1, kt + 32);
    __syncthreads();
    COMPUTE_Y(As0, Bs0);
    COMPUTE_Y(As1, Bs1);
    __syncthreads();
  }
#undef STAGE_Y
#undef COMPUTE_Y

  const int lr = (lane >> 4) * 4;
  const int lc = lane & 15;
#pragma unroll
  for (int i = 0; i < 4; ++i) {
#pragma unroll
    for (int r = 0; r < 4; ++r) {
      int m = wm + i * 16 + lr + r;
      if (m0 + m < cnt) {
        int slot = off + m0 + m;
        float w = w_flat[slot];
        size_t base = (size_t)slot * HID + (size_t)(n0 + wn + lc);
#pragma unroll
        for (int j = 0; j < 4; ++j) Yf[base + j * 16] = f2bf(w * acc[i][j][r]);
      }
    }
  }
}

// ---------------- combine: out[t] = Yf[slot0] + Yf[slot1] ----------------
__global__ __launch_bounds__(256) void combine_kernel(const unsigned short* __restrict__ Yf,
                                                      const int* __restrict__ tok_slot,
                                                      float* __restrict__ out) {
  const int t = blockIdx.x;
  const int c = threadIdx.x * 8;
  const int s0 = tok_slot[2 * t];
  const int s1 = tok_slot[2 * t + 1];
  const ushort4* p0 = reinterpret_cast<const ushort4*>(Yf + (size_t)s0 * HID + c);
  const ushort4* p1 = reinterpret_cast<const ushort4*>(Yf + (size_t)s1 * HID + c);
  ushort4 a0 = p0[0], a1 = p0[1];
  ushort4 b0 = p1[0], b1 = p1[1];
  float4 o0, o1;
  o0.x = bf2f(a0.x) + bf2f(b0.x);
  o0.y = bf2f(a0.y) + bf2f(b0.y);
  o0.z = bf2f(a0.z) + bf2f(b0.z);
  o0.w = bf2f(a0.w) + bf2f(b0.w);
  o1.x = bf2f(a1.x) + bf2f(b1.x);
  o1.y = bf2f(a1.y) + bf2f(b1.y);
  o1.z = bf2f(a1.z) + bf2f(b1.z);
  o1.w = bf2f(a1.w) + bf2f(b1.w);
  float4* op = reinterpret_cast<float4*>(out + (size_t)t * HID + c);
  op[0] = o0;
  op[1] = o1;
}

// ---------------- launch ----------------
extern "C" void kernel_launch(void* const* d_in, const int* in_sizes, int n_in,
                              void* d_out, int out_size, void* d_ws, size_t ws_size,
                              hipStream_t stream) {
  const float* x  = (const float*)d_in[0];
  const float* gw = (const float*)d_in[1];
  const float* wg = (const float*)d_in[2];
  const float* wu = (const float*)d_in[3];
  const float* wd = (const float*)d_in[4];
  float* out = (float*)d_out;
  char* ws = (char*)d_ws;

  // ws layout (bytes) — identical to r5-passing layout
  int*   counts   = (int*)(ws + 0);          // 64
  int*   offsets  = (int*)(ws + 128);        // 64
  int*   n_tiles  = (int*)(ws + 192);        // 4
  int*   tile_map = (int*)(ws + 256);        // <=144*4
  int*   te       = (int*)(ws + 1024);       // 64 KiB
  float* tw       = (float*)(ws + 66560);    // 64 KiB
  int*   tok_flat = (int*)(ws + 132096);     // 64 KiB
  float* w_flat   = (float*)(ws + 197632);   // 64 KiB
  unsigned short* Xb  = (unsigned short*)(ws + 263168);     // 32 MiB
  unsigned short* Wgb = (unsigned short*)(ws + 33817600);   // 48 MiB
  unsigned short* Wub = (unsigned short*)(ws + 84149248);   // 48 MiB
  unsigned short* Wdb = (unsigned short*)(ws + 134480896);  // 48 MiB
  unsigned short* Hf  = (unsigned short*)(ws + 184812544);  // 24 MiB
  int*   tok_slot = (int*)(ws + 209978368);  // 64 KiB
  // Yf [16384][2048] bf16 = 64 MiB, aliases Wgb+Wub (dead after gemm_gu)
  unsigned short* Yf  = Wgb;

  cvt_kernel<<<2048, 256, 0, stream>>>(wg, Wgb, NEXP * INTER * HID);
  cvt_kernel<<<2048, 256, 0, stream>>>(wu, Wub, NEXP * INTER * HID);
  cvt_kernel<<<2048, 256, 0, stream>>>(wd, Wdb, NEXP * HID * INTER);

  router_kernel<<<NTOK / 8, 256, 0, stream>>>(x, gw, te, tw, Xb);
  build_kernel<<<1, 256, 0, stream>>>(te, tw, counts, offsets, tok_flat, w_flat,
                                      tok_slot, tile_map, n_tiles);

  gemm_gu_kernel<<<144 * 6, 256, 0, stream>>>(
      Xb, Wgb, Wub, counts, offsets, tok_flat, tile_map, n_tiles, Hf);
  gemm_y_kernel<<<144 * 16, 256, 0, stream>>>(
      Hf, Wdb, counts, offsets, w_flat, tile_map, n_tiles, Yf);
  combine_kernel<<<NTOK, 256, 0, stream>>>(Yf, tok_slot, out);
}